// Round 12
// baseline (447.858 us; speedup 1.0000x reference)
//
#include <hip/hip_runtime.h>

// ---- problem constants ----
#define NN     20000   // nodes
#define HDIM   256     // hidden
#define RT     4       // relation types
#define KS     8       // symptom channels
#define NHEAD  4
#define HDHEAD 64
#define NE     320000  // edges
#define NSEG   (RT * NN)   // 80000 segments
#define LN_EPS 1e-5f
// SCALE = sqrt(64) = 8

typedef __attribute__((ext_vector_type(8))) short short8;            // 8 bf16 = 4 VGPRs
typedef __attribute__((ext_vector_type(8))) unsigned short ushort8;  // 8 bf16
typedef __attribute__((ext_vector_type(4))) float f32x4;

// ---- workspace layout (BYTE offsets), liveness-reused, total ~172.4 MB ----
static constexpr size_t OFFB_QKV  = 0;
static constexpr size_t OFFB_MIX  = 0;
static constexpr size_t OFFB_HNEW = 0;           // bf16 (N,H) 10.24M (over dead mixb)
static constexpr size_t OFFB_CATB = 81920000;    // 81.92M bf16 (N,K*H)
static constexpr size_t OFFB_HID  = 122880000;   // bf16 (N,H) 10.24M (phase 1 only)
static constexpr size_t OFFB_AGGB = 122880000;   // bf16 (N,R*H) 40.96M
static constexpr size_t OFFB_HB   = 163840000;   // bf16 h (N,H) 10.24M
static constexpr size_t OFFB_GATE = 174080000;   // fp32 (N,KS) 640K
static constexpr size_t OFFB_WQKV = 174720000;   // bf16 [3][RT][H][H] 1,572,864
static constexpr size_t OFFB_W1   = 176292864;   // bf16 (H,H) 131,072
static constexpr size_t OFFB_WSYM = 176423936;   // bf16 (K,H,H) 1,048,576
static constexpr size_t OFFB_WX   = 177472512;   // bf16 (H,K*H) 1,048,576
static constexpr size_t OFFB_SYMW = 178521088;   // fp32 (K,R) pad 256
static constexpr size_t OFFB_CNT  = 178521344;   // int [NSEG] 320,000
static constexpr size_t OFFB_RP   = 178841344;   // int [NSEG+1] pad 320,016
static constexpr size_t OFFB_BSUM = 179161360;   // int [128] 512
static constexpr size_t OFFB_CUR  = 179161872;   // int [NSEG] 320,000
static constexpr size_t OFFB_ESRC = 179481872;   // int [NE] 1,280,000 (src id per CSR slot)
// end = 180,761,872 B (~172.4 MiB)

// ---- helpers ----
__device__ inline ushort f2bf(float f) {
    unsigned u = __float_as_uint(f);
    unsigned r = (u + 0x7FFFu + ((u >> 16) & 1u)) >> 16;
    return (ushort)r;
}
__device__ inline float bf2f(ushort u) { return __uint_as_float(((unsigned)u) << 16); }

// direct global->LDS DMA, 16B per lane. lds dest = wave-uniform base + lane*16.
__device__ inline void gload_lds16(const ushort* g, ushort* l) {
    __builtin_amdgcn_global_load_lds(
        (const __attribute__((address_space(1))) void*)g,
        (__attribute__((address_space(3))) void*)l, 16, 0, 0);
}

// ======================================================================
// f32 -> bf16 convert (4 elems/thread)
// ======================================================================
__global__ __launch_bounds__(256) void cvt_bf16_kernel(
    const float* __restrict__ in, ushort* __restrict__ out, int n4)
{
    int g = blockIdx.x * 256 + threadIdx.x;
    if (g >= n4) return;
    float4 v = *(const float4*)(in + (size_t)g * 4);
    ushort4 o;
    o.x = f2bf(v.x); o.y = f2bf(v.y); o.z = f2bf(v.z); o.w = f2bf(v.w);
    *(ushort4*)(out + (size_t)g * 4) = o;
}

// softmax over R of sym_edge_logits rows -> symw (K x R)
__global__ void symw_kernel(const float* __restrict__ logits, float* __restrict__ symw)
{
    int k = threadIdx.x;
    if (k >= KS) return;
    float v[RT]; float m = -1e30f;
    #pragma unroll
    for (int r = 0; r < RT; ++r) { v[r] = logits[k * RT + r]; m = fmaxf(m, v[r]); }
    float ssum = 0.f;
    #pragma unroll
    for (int r = 0; r < RT; ++r) { v[r] = __expf(v[r] - m); ssum += v[r]; }
    #pragma unroll
    for (int r = 0; r < RT; ++r) symw[k * RT + r] = v[r] / ssum;
}

// ======================================================================
// CSR build: histogram -> 2-level exclusive scan -> reorder
// ======================================================================
__global__ __launch_bounds__(256) void hist_kernel(
    const int* __restrict__ edge_index, const int* __restrict__ edge_type,
    int* __restrict__ cnt)
{
    int e = blockIdx.x * 256 + threadIdx.x;
    if (e >= NE) return;
    int seg = edge_type[e] * NN + edge_index[NE + e];
    atomicAdd(&cnt[seg], 1);
}

__global__ __launch_bounds__(256) void scan1_kernel(
    const int* __restrict__ cnt, int* __restrict__ rp, int* __restrict__ bsum)
{
    __shared__ int sh[256];
    int t = threadIdx.x;
    int base = blockIdx.x * 1024 + t * 4;
    int a0 = (base + 0 < NSEG) ? cnt[base + 0] : 0;
    int a1 = (base + 1 < NSEG) ? cnt[base + 1] : 0;
    int a2 = (base + 2 < NSEG) ? cnt[base + 2] : 0;
    int a3 = (base + 3 < NSEG) ? cnt[base + 3] : 0;
    int s = a0 + a1 + a2 + a3;
    sh[t] = s;
    __syncthreads();
    for (int off = 1; off < 256; off <<= 1) {
        int v = (t >= off) ? sh[t - off] : 0;
        __syncthreads();
        sh[t] += v;
        __syncthreads();
    }
    int excl = sh[t] - s;
    if (t == 255) bsum[blockIdx.x] = sh[255];
    if (base + 0 < NSEG) rp[base + 0] = excl;
    if (base + 1 < NSEG) rp[base + 1] = excl + a0;
    if (base + 2 < NSEG) rp[base + 2] = excl + a0 + a1;
    if (base + 3 < NSEG) rp[base + 3] = excl + a0 + a1 + a2;
}

__global__ __launch_bounds__(256) void scan2_kernel(int* __restrict__ bsum, int nb)
{
    __shared__ int sh[256];
    int t = threadIdx.x;
    int v = (t < nb) ? bsum[t] : 0;
    sh[t] = v;
    __syncthreads();
    for (int off = 1; off < 256; off <<= 1) {
        int u = (t >= off) ? sh[t - off] : 0;
        __syncthreads();
        sh[t] += u;
        __syncthreads();
    }
    if (t < nb) bsum[t] = sh[t] - v;   // exclusive
}

__global__ __launch_bounds__(256) void scan3_kernel(
    int* __restrict__ rp, const int* __restrict__ bsum, int* __restrict__ cursor)
{
    int i = blockIdx.x * 256 + threadIdx.x;
    if (i == 0) rp[NSEG] = NE;
    if (i >= NSEG) return;
    int v = rp[i] + bsum[i >> 10];
    rp[i] = v;
    cursor[i] = v;
}

// store src node id directly into CSR slot (kills one indirection in attn)
__global__ __launch_bounds__(256) void reorder_kernel(
    const int* __restrict__ edge_index, const int* __restrict__ edge_type,
    int* __restrict__ cursor, int* __restrict__ esrc)
{
    int e = blockIdx.x * 256 + threadIdx.x;
    if (e >= NE) return;
    int seg = edge_type[e] * NN + edge_index[NE + e];
    int pos = atomicAdd(&cursor[seg], 1);
    esrc[pos] = edge_index[e];
}

// ======================================================================
// Gather attention: ONE WAVE per segment, all 4 heads at once (64 lanes x
// 4 elems = full 256-dim row). Single pass, online softmax, 2-way
// unrolled with DUAL independent accumulator chains; merged at end.
// ======================================================================
__global__ __launch_bounds__(256) void attn_kernel(
    const ushort* __restrict__ qkv, const int* __restrict__ esrc,
    const int* __restrict__ rp, ushort* __restrict__ aggb)
{
    int seg  = blockIdx.x * 4 + (threadIdx.x >> 6);   // 4 waves/block, grid exact
    int lane = threadIdx.x & 63;
    int t = seg / NN;
    int d = seg - t * NN;
    ushort* outp = aggb + (size_t)d * (RT * HDIM) + t * HDIM + lane * 4;

    int begin = rp[seg], end = rp[seg + 1];
    if (begin == end) {               // empty segment -> zeros (matches segment_sum)
        ushort4 z; z.x = 0; z.y = 0; z.z = 0; z.w = 0;
        *(ushort4*)outp = z;
        return;
    }

    const size_t sMat = (size_t)RT * NN * HDIM;
    const ushort* Kbase = qkv + sMat     + (size_t)t * NN * HDIM + lane * 4;
    const ushort* Vbase = qkv + 2 * sMat + (size_t)t * NN * HDIM + lane * 4;

    ushort4 q4 = *(const ushort4*)(qkv + ((size_t)t * NN + d) * HDIM + lane * 4);
    float qx = bf2f(q4.x), qy = bf2f(q4.y), qz = bf2f(q4.z), qw = bf2f(q4.w);

    float mx0 = -1e30f, den0 = 0.f, a00 = 0.f, a01 = 0.f, a02 = 0.f, a03 = 0.f;
    float mx1 = -1e30f, den1 = 0.f, a10 = 0.f, a11 = 0.f, a12 = 0.f, a13 = 0.f;

    int p = begin;
    for (; p + 2 <= end; p += 2) {
        int s0 = esrc[p];
        int s1 = esrc[p + 1];
        ushort4 k0 = *(const ushort4*)(Kbase + (size_t)s0 * HDIM);
        ushort4 k1 = *(const ushort4*)(Kbase + (size_t)s1 * HDIM);
        ushort4 v0 = *(const ushort4*)(Vbase + (size_t)s0 * HDIM);
        ushort4 v1 = *(const ushort4*)(Vbase + (size_t)s1 * HDIM);
        float p0 = qx * bf2f(k0.x) + qy * bf2f(k0.y) + qz * bf2f(k0.z) + qw * bf2f(k0.w);
        float p1 = qx * bf2f(k1.x) + qy * bf2f(k1.y) + qz * bf2f(k1.z) + qw * bf2f(k1.w);
        p0 += __shfl_xor(p0, 1); p1 += __shfl_xor(p1, 1);
        p0 += __shfl_xor(p0, 2); p1 += __shfl_xor(p1, 2);
        p0 += __shfl_xor(p0, 4); p1 += __shfl_xor(p1, 4);
        p0 += __shfl_xor(p0, 8); p1 += __shfl_xor(p1, 8);
        p0 *= 0.125f;            p1 *= 0.125f;
        float nm0 = fmaxf(mx0, p0),      nm1 = fmaxf(mx1, p1);
        float c0  = __expf(mx0 - nm0),   c1  = __expf(mx1 - nm1);
        float w0  = __expf(p0 - nm0),    w1  = __expf(p1 - nm1);
        den0 = den0 * c0 + w0;           den1 = den1 * c1 + w1;
        a00 = a00 * c0 + w0 * bf2f(v0.x); a10 = a10 * c1 + w1 * bf2f(v1.x);
        a01 = a01 * c0 + w0 * bf2f(v0.y); a11 = a11 * c1 + w1 * bf2f(v1.y);
        a02 = a02 * c0 + w0 * bf2f(v0.z); a12 = a12 * c1 + w1 * bf2f(v1.z);
        a03 = a03 * c0 + w0 * bf2f(v0.w); a13 = a13 * c1 + w1 * bf2f(v1.w);
        mx0 = nm0;                        mx1 = nm1;
    }
    if (p < end) {   // odd tail -> chain 0
        int s0 = esrc[p];
        ushort4 k0 = *(const ushort4*)(Kbase + (size_t)s0 * HDIM);
        ushort4 v0 = *(const ushort4*)(Vbase + (size_t)s0 * HDIM);
        float p0 = qx * bf2f(k0.x) + qy * bf2f(k0.y) + qz * bf2f(k0.z) + qw * bf2f(k0.w);
        p0 += __shfl_xor(p0, 1); p0 += __shfl_xor(p0, 2);
        p0 += __shfl_xor(p0, 4); p0 += __shfl_xor(p0, 8);
        p0 *= 0.125f;
        float nm0 = fmaxf(mx0, p0);
        float c0  = __expf(mx0 - nm0);
        float w0  = __expf(p0 - nm0);
        den0 = den0 * c0 + w0;
        a00 = a00 * c0 + w0 * bf2f(v0.x);
        a01 = a01 * c0 + w0 * bf2f(v0.y);
        a02 = a02 * c0 + w0 * bf2f(v0.z);
        a03 = a03 * c0 + w0 * bf2f(v0.w);
        mx0 = nm0;
    }
    // merge the two chains (chain1 empty -> c1 = exp(-1e30-m) = 0)
    float m  = fmaxf(mx0, mx1);
    float c0 = __expf(mx0 - m), c1 = __expf(mx1 - m);
    float den = den0 * c0 + den1 * c1;
    float inv = 1.0f / den;
    ushort4 o;
    o.x = f2bf((a00 * c0 + a10 * c1) * inv);
    o.y = f2bf((a01 * c0 + a11 * c1) * inv);
    o.z = f2bf((a02 * c0 + a12 * c1) * inv);
    o.w = f2bf((a03 * c0 + a13 * c1) * inv);
    *(ushort4*)outp = o;
}

// ======================================================================
// mix: mixb[k][n][h] = sum_r symw[k,r] * aggb[n][r*H + h]   (bf16 out)
// ======================================================================
__global__ __launch_bounds__(256) void mix_kernel(
    const ushort* __restrict__ aggb, const float* __restrict__ symw,
    ushort* __restrict__ mixb)
{
    __shared__ float sw[KS * RT];
    if (threadIdx.x < KS * RT) sw[threadIdx.x] = symw[threadIdx.x];
    __syncthreads();
    int g = blockIdx.x * 256 + threadIdx.x;
    if (g >= NN * HDIM / 8) return;
    int n  = g >> 5;
    int c8 = (g & 31) * 8;
    const ushort* base = aggb + (size_t)n * (RT * HDIM) + c8;
    ushort8 u0 = *(const ushort8*)(base);
    ushort8 u1 = *(const ushort8*)(base + HDIM);
    ushort8 u2 = *(const ushort8*)(base + 2 * HDIM);
    ushort8 u3 = *(const ushort8*)(base + 3 * HDIM);
    float f0[8], f1[8], f2[8], f3[8];
    #pragma unroll
    for (int j = 0; j < 8; ++j) {
        f0[j] = bf2f((ushort)u0[j]); f1[j] = bf2f((ushort)u1[j]);
        f2[j] = bf2f((ushort)u2[j]); f3[j] = bf2f((ushort)u3[j]);
    }
    #pragma unroll
    for (int k = 0; k < KS; ++k) {
        float w0 = sw[k * RT + 0], w1 = sw[k * RT + 1];
        float w2 = sw[k * RT + 2], w3 = sw[k * RT + 3];
        ushort8 o;
        #pragma unroll
        for (int j = 0; j < 8; ++j)
            o[j] = f2bf(w0 * f0[j] + w1 * f1[j] + w2 * f2[j] + w3 * f3[j]);
        *(ushort8*)(mixb + (size_t)k * NN * HDIM + (size_t)n * HDIM + c8) = o;
    }
}

// ======================================================================
// bf16 MFMA GEMM: C[m][n] = sum_k A[m][k]*B[n][k]; 128x128 tile, BK=32,
// 4 waves x (64x64). K-loop IDENTICAL to the proven round-7/10 version
// (single-buffer, 2 barriers/step, pre-swizzled global_load_lds).
// ONLY change: LDS halved 32KB -> 16KB. The C-tile epilogue repacks in
// TWO 64-row halves (waves of that half write acc -> barrier -> all
// threads do coalesced 16B stores -> barrier). Raises blocks/CU.
// Epilogue: +bias, relu, optional gate. Output bf16. K%32==0.
// ======================================================================
__global__ __launch_bounds__(256) void gemm_bf16_nt(
    const ushort* __restrict__ A, const ushort* __restrict__ B,
    const float* __restrict__ bias, const float* __restrict__ gatep,
    ushort* __restrict__ Cout,
    int M, int Kd, int lda, int ldb, int ldc,
    long long sA, long long sB, long long sBias, long long sC,
    int relu, int gate_mode)
{
    const int z = blockIdx.z;
    A += (size_t)z * sA;
    B += (size_t)z * sB;
    if (bias) bias += (size_t)z * sBias;

    __shared__ ushort smem[8192];   // 16 KB: As(8K)+Bs(8K) in loop; 64-row C-half after
    ushort* As = smem;
    ushort* Bs = smem + 4096;

    const int tid  = threadIdx.x;
    const int lane = tid & 63;
    const int wid  = tid >> 6;
    const int wr   = (wid >> 1) * 64;
    const int wc   = (wid & 1) * 64;
    const int bm   = blockIdx.x * 128;
    const int bn   = blockIdx.y * 128;

    f32x4 acc[4][4];
    #pragma unroll
    for (int m = 0; m < 4; ++m)
        #pragma unroll
        for (int n = 0; n < 4; ++n)
            #pragma unroll
            for (int e = 0; e < 4; ++e) acc[m][n][e] = 0.f;

    const int r0    = lane & 15;
    const int slotq = lane >> 4;          // logical 16B k-slot (0..3)

    // staging geometry: chunk = 1KB = 16 rows x 64B; row/col fixed per lane
    const int srow0 = ((wid << 1) << 4) + (lane >> 2);       // chunk c=0 row
    const int scol0 = (((lane & 3) ^ ((srow0 >> 1) & 3)) << 3);
    const int srow1 = srow0 + 16;                            // chunk c=1 row
    const int scol1 = (((lane & 3) ^ ((srow1 >> 1) & 3)) << 3);
    const int ga0 = bm + srow0 < M ? bm + srow0 : M - 1;
    const int ga1 = bm + srow1 < M ? bm + srow1 : M - 1;

    for (int k0 = 0; k0 < Kd; k0 += 32) {
        gload_lds16(A + (size_t)ga0 * lda + k0 + scol0, &As[(wid << 1) * 512]);
        gload_lds16(A + (size_t)ga1 * lda + k0 + scol1, &As[((wid << 1) + 1) * 512]);
        gload_lds16(B + (size_t)(bn + srow0) * ldb + k0 + scol0, &Bs[(wid << 1) * 512]);
        gload_lds16(B + (size_t)(bn + srow1) * ldb + k0 + scol1, &Bs[((wid << 1) + 1) * 512]);
        __syncthreads();
        short8 a[4], b[4];
        #pragma unroll
        for (int m = 0; m < 4; ++m) {
            int rr = wr + m * 16 + r0;
            a[m] = *(const short8*)(&As[rr * 32 + ((slotq ^ ((rr >> 1) & 3)) << 3)]);
        }
        #pragma unroll
        for (int n = 0; n < 4; ++n) {
            int rr = wc + n * 16 + r0;
            b[n] = *(const short8*)(&Bs[rr * 32 + ((slotq ^ ((rr >> 1) & 3)) << 3)]);
        }
        #pragma unroll
        for (int m = 0; m < 4; ++m)
            #pragma unroll
            for (int n = 0; n < 4; ++n)
                acc[m][n] = __builtin_amdgcn_mfma_f32_16x16x32_bf16(a[m], b[n], acc[m][n], 0, 0, 0);
        __syncthreads();
    }

    // ---- epilogue: two 64-row halves through 16KB LDS ----
    const int cr = (lane >> 4) * 4;
    const int cc = lane & 15;
    #pragma unroll
    for (int half = 0; half < 2; ++half) {
        if ((wid >> 1) == half) {          // waves owning rows half*64..half*64+63
            #pragma unroll
            for (int m = 0; m < 4; ++m) {
                #pragma unroll
                for (int j = 0; j < 4; ++j) {
                    int row  = wr + m * 16 + cr + j;   // global row in tile
                    int lrow = row - half * 64;        // 0..63
                    int grow = bm + row;
                    float g = 1.0f;
                    if (gate_mode) g = (grow < M) ? gatep[(size_t)grow * KS + z] : 0.f;
                    int sw = ((row >> 2) & 3) << 5;    // == ((lrow>>2)&3)<<5 (64%4-group aligned)
                    #pragma unroll
                    for (int n = 0; n < 4; ++n) {
                        int col = wc + n * 16 + cc;
                        float v = acc[m][n][j];
                        if (bias) v += bias[bn + col];
                        if (relu) v = fmaxf(v, 0.f);
                        v *= g;
                        *(ushort*)((char*)smem + lrow * 256 + ((col * 2) ^ sw)) = f2bf(v);
                    }
                }
            }
        }
        __syncthreads();
        #pragma unroll
        for (int it = 0; it < 4; ++it) {
            int lrow = it * 16 + (tid >> 4);
            int row  = half * 64 + lrow;
            int grow = bm + row;
            int sw   = ((row >> 2) & 3) << 5;
            ushort8 vv = *(const ushort8*)((const char*)smem + lrow * 256 + (((tid & 15) * 16) ^ sw));
            if (grow < M)
                *(ushort8*)(Cout + (size_t)z * sC + (size_t)grow * ldc + bn + (tid & 15) * 8) = vv;
        }
        __syncthreads();
    }
}

// gate: logits = hid @ w2.T + b2 ; softmax over K. One wave per node. hid bf16.
__global__ __launch_bounds__(256) void gate_kernel(
    const ushort* __restrict__ hid, const float* __restrict__ w2,
    const float* __restrict__ b2, float* __restrict__ gate)
{
    int wid = threadIdx.x >> 6, lane = threadIdx.x & 63;
    int n = blockIdx.x * 4 + wid;
    if (n >= NN) return;
    ushort4 h4 = *(const ushort4*)(hid + (size_t)n * HDIM + lane * 4);
    float hx = bf2f(h4.x), hy = bf2f(h4.y), hz = bf2f(h4.z), hw = bf2f(h4.w);
    float lg[KS];
    #pragma unroll
    for (int k = 0; k < KS; ++k) {
        const float4 wv = *(const float4*)(w2 + k * HDIM + lane * 4);
        float p = hx * wv.x + hy * wv.y + hz * wv.z + hw * wv.w;
        #pragma unroll
        for (int m = 1; m < 64; m <<= 1) p += __shfl_xor(p, m);
        lg[k] = p + b2[k];
    }
    float m = lg[0];
    #pragma unroll
    for (int k = 1; k < KS; ++k) m = fmaxf(m, lg[k]);
    float ssum = 0.f;
    #pragma unroll
    for (int k = 0; k < KS; ++k) ssum += __expf(lg[k] - m);
    float inv = 1.0f / ssum;
    #pragma unroll
    for (int k = 0; k < KS; ++k)
        if (lane == k) gate[(size_t)n * KS + k] = __expf(lg[k] - m) * inv;
}

// residual + layernorm. One wave per node. hnew bf16.
__global__ __launch_bounds__(256) void ln_kernel(
    const float* __restrict__ h, const ushort* __restrict__ hnew,
    const float* __restrict__ gamma, const float* __restrict__ beta,
    float* __restrict__ out)
{
    int wid = threadIdx.x >> 6, lane = threadIdx.x & 63;
    int n = blockIdx.x * 4 + wid;
    if (n >= NN) return;
    size_t off = (size_t)n * HDIM + lane * 4;
    const float4 a = *(const float4*)(h + off);
    ushort4 b4 = *(const ushort4*)(hnew + off);
    float4 x = make_float4(a.x + bf2f(b4.x), a.y + bf2f(b4.y),
                           a.z + bf2f(b4.z), a.w + bf2f(b4.w));
    float s1 = x.x + x.y + x.z + x.w;
    float s2 = x.x * x.x + x.y * x.y + x.z * x.z + x.w * x.w;
    #pragma unroll
    for (int m = 1; m < 64; m <<= 1) { s1 += __shfl_xor(s1, m); s2 += __shfl_xor(s2, m); }
    float mu = s1 * (1.0f / HDIM);
    float var = s2 * (1.0f / HDIM) - mu * mu;
    float inv = rsqrtf(var + LN_EPS);
    const float4 g  = *(const float4*)(gamma + lane * 4);
    const float4 be = *(const float4*)(beta + lane * 4);
    float4 o;
    o.x = (x.x - mu) * inv * g.x + be.x;
    o.y = (x.y - mu) * inv * g.y + be.y;
    o.z = (x.z - mu) * inv * g.z + be.z;
    o.w = (x.w - mu) * inv * g.w + be.w;
    *(float4*)(out + off) = o;
}

extern "C" void kernel_launch(void* const* d_in, const int* in_sizes, int n_in,
                              void* d_out, int out_size, void* d_ws, size_t ws_size,
                              hipStream_t stream) {
    const float* h          = (const float*)d_in[0];
    const int*   edge_index = (const int*)d_in[1];
    const int*   edge_type  = (const int*)d_in[2];
    const float* W_q        = (const float*)d_in[3];
    const float* W_k        = (const float*)d_in[4];
    const float* W_v        = (const float*)d_in[5];
    const float* mlp_w1     = (const float*)d_in[6];
    const float* mlp_b1     = (const float*)d_in[7];
    const float* mlp_w2     = (const float*)d_in[8];
    const float* mlp_b2     = (const float*)d_in[9];
    const float* sym_logits = (const float*)d_in[10];
    const float* W_sym      = (const float*)d_in[11];
    const float* b_sym      = (const float*)d_in[12];
    const float* W_cross    = (const float*)d_in[13];
    const float* b_cross    = (const float*)d_in[14];
    const float* ln_gamma   = (const float*)d_in[15];
    const float* ln_beta    = (const float*)d_in[16];
    float* out = (float*)d_out;
    char*  ws  = (char*)d_ws;

    ushort* qkv    = (ushort*)(ws + OFFB_QKV);
    ushort* mixb   = (ushort*)(ws + OFFB_MIX);
    ushort* hnew   = (ushort*)(ws + OFFB_HNEW);
    ushort* catb   = (ushort*)(ws + OFFB_CATB);
    ushort* hid    = (ushort*)(ws + OFFB_HID);
    ushort* aggb   = (ushort*)(ws + OFFB_AGGB);
    ushort* hb     = (ushort*)(ws + OFFB_HB);
    float*  gate   = (float*)(ws + OFFB_GATE);
    ushort* wqkvb  = (ushort*)(ws + OFFB_WQKV);
    ushort* w1b    = (ushort*)(ws + OFFB_W1);
    ushort* wsymb  = (ushort*)(ws + OFFB_WSYM);
    ushort* wxb    = (ushort*)(ws + OFFB_WX);
    float*  symw   = (float*)(ws + OFFB_SYMW);
    int*    cnt    = (int*)(ws + OFFB_CNT);
    int*    rp     = (int*)(ws + OFFB_RP);
    int*    bsum   = (int*)(ws + OFFB_BSUM);
    int*    cursor = (int*)(ws + OFFB_CUR);
    int*    esrc   = (int*)(ws + OFFB_ESRC);

    const long long sRHH = (long long)RT * HDIM * HDIM;   // per-mat weight stride
    const long long sNH  = (long long)NN * HDIM;          // per-z output stride

    // ---- conversions ----
    cvt_bf16_kernel<<<5000, 256, 0, stream>>>(h, hb, NN * HDIM / 4);
    cvt_bf16_kernel<<<256, 256, 0, stream>>>(W_q, wqkvb,            RT * HDIM * HDIM / 4);
    cvt_bf16_kernel<<<256, 256, 0, stream>>>(W_k, wqkvb + sRHH,     RT * HDIM * HDIM / 4);
    cvt_bf16_kernel<<<256, 256, 0, stream>>>(W_v, wqkvb + 2 * sRHH, RT * HDIM * HDIM / 4);
    cvt_bf16_kernel<<<64, 256, 0, stream>>>(mlp_w1, w1b, HDIM * HDIM / 4);
    cvt_bf16_kernel<<<512, 256, 0, stream>>>(W_sym, wsymb, KS * HDIM * HDIM / 4);
    cvt_bf16_kernel<<<512, 256, 0, stream>>>(W_cross, wxb, HDIM * KS * HDIM / 4);
    symw_kernel<<<1, 64, 0, stream>>>(sym_logits, symw);

    // ---- routing MLP -> gate ----
    gemm_bf16_nt<<<dim3(157, 2, 1), 256, 0, stream>>>(hb, w1b, mlp_b1, nullptr, hid,
        NN, HDIM, HDIM, HDIM, HDIM, 0, 0, 0, 0, 1, 0);
    gate_kernel<<<NN / 4, 256, 0, stream>>>(hid, mlp_w2, mlp_b2, gate);

    // ---- CSR build over seg = t*N + dst ----
    hipMemsetAsync(cnt, 0, NSEG * sizeof(int), stream);
    hist_kernel<<<NE / 256, 256, 0, stream>>>(edge_index, edge_type, cnt);
    scan1_kernel<<<79, 256, 0, stream>>>(cnt, rp, bsum);
    scan2_kernel<<<1, 256, 0, stream>>>(bsum, 79);
    scan3_kernel<<<313, 256, 0, stream>>>(rp, bsum, cursor);
    reorder_kernel<<<NE / 256, 256, 0, stream>>>(edge_index, edge_type, cursor, esrc);

    // ---- QKV for all 3 mats x 4 relations in one batched GEMM (z = mat*4+t) ----
    gemm_bf16_nt<<<dim3(157, 2, 12), 256, 0, stream>>>(hb, wqkvb, nullptr, nullptr, qkv,
        NN, HDIM, HDIM, HDIM, HDIM, 0, (long long)HDIM * HDIM, 0, sNH, 0, 0);

    // ---- gather attention: one wave per segment, single pass, dual chains ----
    attn_kernel<<<NSEG / 4, 256, 0, stream>>>(qkv, esrc, rp, aggb);

    // ---- symw mix: mixb (K,N,H) bf16, over dead QKV ----
    mix_kernel<<<NN * HDIM / 8 / 256, 256, 0, stream>>>(aggb, symw, mixb);

    // ---- symptom GEMM, z=k: catb[n, z*256+col] = relu(mixb_z @ Wsym_z.T + b_sym_z)*gate ----
    gemm_bf16_nt<<<dim3(157, 2, KS), 256, 0, stream>>>(mixb, wsymb, b_sym, gate, catb,
        NN, HDIM, HDIM, HDIM, KS * HDIM,
        sNH, (long long)HDIM * HDIM, HDIM, HDIM, 1, 1);

    // ---- cross GEMM: hnew = relu(catb @ W_cross.T + b_cross), bf16 out ----
    gemm_bf16_nt<<<dim3(157, 2, 1), 256, 0, stream>>>(catb, wxb, b_cross, nullptr, hnew,
        NN, KS * HDIM, KS * HDIM, KS * HDIM, HDIM, 0, 0, 0, 0, 1, 0);

    // ---- residual + layernorm ----
    ln_kernel<<<NN / 4, 256, 0, stream>>>(h, hnew, ln_gamma, ln_beta, out);
}

// Round 13
// 385.131 us; speedup vs baseline: 1.1629x; 1.1629x over previous
//
#include <hip/hip_runtime.h>

// ---- problem constants ----
#define NN     20000   // nodes
#define HDIM   256     // hidden
#define RT     4       // relation types
#define KS     8       // symptom channels
#define NHEAD  4
#define HDHEAD 64
#define NE     320000  // edges
#define NSEG   (RT * NN)   // 80000 segments
#define LN_EPS 1e-5f
// SCALE = sqrt(64) = 8

typedef __attribute__((ext_vector_type(8))) short short8;            // 8 bf16 = 4 VGPRs
typedef __attribute__((ext_vector_type(8))) unsigned short ushort8;  // 8 bf16
typedef __attribute__((ext_vector_type(4))) float f32x4;

// ---- workspace layout (BYTE offsets), liveness-reused, total ~172.4 MB ----
static constexpr size_t OFFB_QKV  = 0;
static constexpr size_t OFFB_MIX  = 0;
static constexpr size_t OFFB_HNEW = 0;           // bf16 (N,H) 10.24M (over dead mixb)
static constexpr size_t OFFB_CATB = 81920000;    // 81.92M bf16 (N,K*H)
static constexpr size_t OFFB_HID  = 122880000;   // bf16 (N,H) 10.24M (phase 1 only)
static constexpr size_t OFFB_AGGB = 122880000;   // bf16 (N,R*H) 40.96M
static constexpr size_t OFFB_HB   = 163840000;   // bf16 h (N,H) 10.24M
static constexpr size_t OFFB_GATE = 174080000;   // fp32 (N,KS) 640K
static constexpr size_t OFFB_WQKV = 174720000;   // bf16 [3][RT][H][H] 1,572,864
static constexpr size_t OFFB_W1   = 176292864;   // bf16 (H,H) 131,072
static constexpr size_t OFFB_WSYM = 176423936;   // bf16 (K,H,H) 1,048,576
static constexpr size_t OFFB_WX   = 177472512;   // bf16 (H,K*H) 1,048,576
static constexpr size_t OFFB_SYMW = 178521088;   // fp32 (K,R) pad 256
static constexpr size_t OFFB_CNT  = 178521344;   // int [NSEG] 320,000
static constexpr size_t OFFB_RP   = 178841344;   // int [NSEG+1] pad 320,016
static constexpr size_t OFFB_BSUM = 179161360;   // int [128] 512
static constexpr size_t OFFB_CUR  = 179161872;   // int [NSEG] 320,000
static constexpr size_t OFFB_ESRC = 179481872;   // int [NE] 1,280,000 (src id per CSR slot)
// end = 180,761,872 B (~172.4 MiB)

// ---- helpers ----
__device__ inline ushort f2bf(float f) {
    unsigned u = __float_as_uint(f);
    unsigned r = (u + 0x7FFFu + ((u >> 16) & 1u)) >> 16;
    return (ushort)r;
}
__device__ inline float bf2f(ushort u) { return __uint_as_float(((unsigned)u) << 16); }

// direct global->LDS DMA, 16B per lane. lds dest = wave-uniform base + lane*16.
__device__ inline void gload_lds16(const ushort* g, ushort* l) {
    __builtin_amdgcn_global_load_lds(
        (const __attribute__((address_space(1))) void*)g,
        (__attribute__((address_space(3))) void*)l, 16, 0, 0);
}

// ======================================================================
// f32 -> bf16 convert (4 elems/thread)
// ======================================================================
__global__ __launch_bounds__(256) void cvt_bf16_kernel(
    const float* __restrict__ in, ushort* __restrict__ out, int n4)
{
    int g = blockIdx.x * 256 + threadIdx.x;
    if (g >= n4) return;
    float4 v = *(const float4*)(in + (size_t)g * 4);
    ushort4 o;
    o.x = f2bf(v.x); o.y = f2bf(v.y); o.z = f2bf(v.z); o.w = f2bf(v.w);
    *(ushort4*)(out + (size_t)g * 4) = o;
}

// softmax over R of sym_edge_logits rows -> symw (K x R)
__global__ void symw_kernel(const float* __restrict__ logits, float* __restrict__ symw)
{
    int k = threadIdx.x;
    if (k >= KS) return;
    float v[RT]; float m = -1e30f;
    #pragma unroll
    for (int r = 0; r < RT; ++r) { v[r] = logits[k * RT + r]; m = fmaxf(m, v[r]); }
    float ssum = 0.f;
    #pragma unroll
    for (int r = 0; r < RT; ++r) { v[r] = __expf(v[r] - m); ssum += v[r]; }
    #pragma unroll
    for (int r = 0; r < RT; ++r) symw[k * RT + r] = v[r] / ssum;
}

// ======================================================================
// CSR build: histogram -> 2-level exclusive scan -> reorder
// ======================================================================
__global__ __launch_bounds__(256) void hist_kernel(
    const int* __restrict__ edge_index, const int* __restrict__ edge_type,
    int* __restrict__ cnt)
{
    int e = blockIdx.x * 256 + threadIdx.x;
    if (e >= NE) return;
    int seg = edge_type[e] * NN + edge_index[NE + e];
    atomicAdd(&cnt[seg], 1);
}

__global__ __launch_bounds__(256) void scan1_kernel(
    const int* __restrict__ cnt, int* __restrict__ rp, int* __restrict__ bsum)
{
    __shared__ int sh[256];
    int t = threadIdx.x;
    int base = blockIdx.x * 1024 + t * 4;
    int a0 = (base + 0 < NSEG) ? cnt[base + 0] : 0;
    int a1 = (base + 1 < NSEG) ? cnt[base + 1] : 0;
    int a2 = (base + 2 < NSEG) ? cnt[base + 2] : 0;
    int a3 = (base + 3 < NSEG) ? cnt[base + 3] : 0;
    int s = a0 + a1 + a2 + a3;
    sh[t] = s;
    __syncthreads();
    for (int off = 1; off < 256; off <<= 1) {
        int v = (t >= off) ? sh[t - off] : 0;
        __syncthreads();
        sh[t] += v;
        __syncthreads();
    }
    int excl = sh[t] - s;
    if (t == 255) bsum[blockIdx.x] = sh[255];
    if (base + 0 < NSEG) rp[base + 0] = excl;
    if (base + 1 < NSEG) rp[base + 1] = excl + a0;
    if (base + 2 < NSEG) rp[base + 2] = excl + a0 + a1;
    if (base + 3 < NSEG) rp[base + 3] = excl + a0 + a1 + a2;
}

__global__ __launch_bounds__(256) void scan2_kernel(int* __restrict__ bsum, int nb)
{
    __shared__ int sh[256];
    int t = threadIdx.x;
    int v = (t < nb) ? bsum[t] : 0;
    sh[t] = v;
    __syncthreads();
    for (int off = 1; off < 256; off <<= 1) {
        int u = (t >= off) ? sh[t - off] : 0;
        __syncthreads();
        sh[t] += u;
        __syncthreads();
    }
    if (t < nb) bsum[t] = sh[t] - v;   // exclusive
}

__global__ __launch_bounds__(256) void scan3_kernel(
    int* __restrict__ rp, const int* __restrict__ bsum, int* __restrict__ cursor)
{
    int i = blockIdx.x * 256 + threadIdx.x;
    if (i == 0) rp[NSEG] = NE;
    if (i >= NSEG) return;
    int v = rp[i] + bsum[i >> 10];
    rp[i] = v;
    cursor[i] = v;
}

// store src node id directly into CSR slot (kills one indirection in attn)
__global__ __launch_bounds__(256) void reorder_kernel(
    const int* __restrict__ edge_index, const int* __restrict__ edge_type,
    int* __restrict__ cursor, int* __restrict__ esrc)
{
    int e = blockIdx.x * 256 + threadIdx.x;
    if (e >= NE) return;
    int seg = edge_type[e] * NN + edge_index[NE + e];
    int pos = atomicAdd(&cursor[seg], 1);
    esrc[pos] = edge_index[e];
}

// ======================================================================
// Gather attention: ONE WAVE per segment, all 4 heads at once (64 lanes x
// 4 elems = full 256-dim row). Single pass, online softmax, 2-way
// unrolled with DUAL independent accumulator chains; merged at end.
// ======================================================================
__global__ __launch_bounds__(256) void attn_kernel(
    const ushort* __restrict__ qkv, const int* __restrict__ esrc,
    const int* __restrict__ rp, ushort* __restrict__ aggb)
{
    int seg  = blockIdx.x * 4 + (threadIdx.x >> 6);   // 4 waves/block, grid exact
    int lane = threadIdx.x & 63;
    int t = seg / NN;
    int d = seg - t * NN;
    ushort* outp = aggb + (size_t)d * (RT * HDIM) + t * HDIM + lane * 4;

    int begin = rp[seg], end = rp[seg + 1];
    if (begin == end) {               // empty segment -> zeros (matches segment_sum)
        ushort4 z; z.x = 0; z.y = 0; z.z = 0; z.w = 0;
        *(ushort4*)outp = z;
        return;
    }

    const size_t sMat = (size_t)RT * NN * HDIM;
    const ushort* Kbase = qkv + sMat     + (size_t)t * NN * HDIM + lane * 4;
    const ushort* Vbase = qkv + 2 * sMat + (size_t)t * NN * HDIM + lane * 4;

    ushort4 q4 = *(const ushort4*)(qkv + ((size_t)t * NN + d) * HDIM + lane * 4);
    float qx = bf2f(q4.x), qy = bf2f(q4.y), qz = bf2f(q4.z), qw = bf2f(q4.w);

    float mx0 = -1e30f, den0 = 0.f, a00 = 0.f, a01 = 0.f, a02 = 0.f, a03 = 0.f;
    float mx1 = -1e30f, den1 = 0.f, a10 = 0.f, a11 = 0.f, a12 = 0.f, a13 = 0.f;

    int p = begin;
    for (; p + 2 <= end; p += 2) {
        int s0 = esrc[p];
        int s1 = esrc[p + 1];
        ushort4 k0 = *(const ushort4*)(Kbase + (size_t)s0 * HDIM);
        ushort4 k1 = *(const ushort4*)(Kbase + (size_t)s1 * HDIM);
        ushort4 v0 = *(const ushort4*)(Vbase + (size_t)s0 * HDIM);
        ushort4 v1 = *(const ushort4*)(Vbase + (size_t)s1 * HDIM);
        float p0 = qx * bf2f(k0.x) + qy * bf2f(k0.y) + qz * bf2f(k0.z) + qw * bf2f(k0.w);
        float p1 = qx * bf2f(k1.x) + qy * bf2f(k1.y) + qz * bf2f(k1.z) + qw * bf2f(k1.w);
        p0 += __shfl_xor(p0, 1); p1 += __shfl_xor(p1, 1);
        p0 += __shfl_xor(p0, 2); p1 += __shfl_xor(p1, 2);
        p0 += __shfl_xor(p0, 4); p1 += __shfl_xor(p1, 4);
        p0 += __shfl_xor(p0, 8); p1 += __shfl_xor(p1, 8);
        p0 *= 0.125f;            p1 *= 0.125f;
        float nm0 = fmaxf(mx0, p0),      nm1 = fmaxf(mx1, p1);
        float c0  = __expf(mx0 - nm0),   c1  = __expf(mx1 - nm1);
        float w0  = __expf(p0 - nm0),    w1  = __expf(p1 - nm1);
        den0 = den0 * c0 + w0;           den1 = den1 * c1 + w1;
        a00 = a00 * c0 + w0 * bf2f(v0.x); a10 = a10 * c1 + w1 * bf2f(v1.x);
        a01 = a01 * c0 + w0 * bf2f(v0.y); a11 = a11 * c1 + w1 * bf2f(v1.y);
        a02 = a02 * c0 + w0 * bf2f(v0.z); a12 = a12 * c1 + w1 * bf2f(v1.z);
        a03 = a03 * c0 + w0 * bf2f(v0.w); a13 = a13 * c1 + w1 * bf2f(v1.w);
        mx0 = nm0;                        mx1 = nm1;
    }
    if (p < end) {   // odd tail -> chain 0
        int s0 = esrc[p];
        ushort4 k0 = *(const ushort4*)(Kbase + (size_t)s0 * HDIM);
        ushort4 v0 = *(const ushort4*)(Vbase + (size_t)s0 * HDIM);
        float p0 = qx * bf2f(k0.x) + qy * bf2f(k0.y) + qz * bf2f(k0.z) + qw * bf2f(k0.w);
        p0 += __shfl_xor(p0, 1); p0 += __shfl_xor(p0, 2);
        p0 += __shfl_xor(p0, 4); p0 += __shfl_xor(p0, 8);
        p0 *= 0.125f;
        float nm0 = fmaxf(mx0, p0);
        float c0  = __expf(mx0 - nm0);
        float w0  = __expf(p0 - nm0);
        den0 = den0 * c0 + w0;
        a00 = a00 * c0 + w0 * bf2f(v0.x);
        a01 = a01 * c0 + w0 * bf2f(v0.y);
        a02 = a02 * c0 + w0 * bf2f(v0.z);
        a03 = a03 * c0 + w0 * bf2f(v0.w);
        mx0 = nm0;
    }
    // merge the two chains (chain1 empty -> c1 = exp(-1e30-m) = 0)
    float m  = fmaxf(mx0, mx1);
    float c0 = __expf(mx0 - m), c1 = __expf(mx1 - m);
    float den = den0 * c0 + den1 * c1;
    float inv = 1.0f / den;
    ushort4 o;
    o.x = f2bf((a00 * c0 + a10 * c1) * inv);
    o.y = f2bf((a01 * c0 + a11 * c1) * inv);
    o.z = f2bf((a02 * c0 + a12 * c1) * inv);
    o.w = f2bf((a03 * c0 + a13 * c1) * inv);
    *(ushort4*)outp = o;
}

// ======================================================================
// mix: mixb[k][n][h] = sum_r symw[k,r] * aggb[n][r*H + h]   (bf16 out)
// ======================================================================
__global__ __launch_bounds__(256) void mix_kernel(
    const ushort* __restrict__ aggb, const float* __restrict__ symw,
    ushort* __restrict__ mixb)
{
    __shared__ float sw[KS * RT];
    if (threadIdx.x < KS * RT) sw[threadIdx.x] = symw[threadIdx.x];
    __syncthreads();
    int g = blockIdx.x * 256 + threadIdx.x;
    if (g >= NN * HDIM / 8) return;
    int n  = g >> 5;
    int c8 = (g & 31) * 8;
    const ushort* base = aggb + (size_t)n * (RT * HDIM) + c8;
    ushort8 u0 = *(const ushort8*)(base);
    ushort8 u1 = *(const ushort8*)(base + HDIM);
    ushort8 u2 = *(const ushort8*)(base + 2 * HDIM);
    ushort8 u3 = *(const ushort8*)(base + 3 * HDIM);
    float f0[8], f1[8], f2[8], f3[8];
    #pragma unroll
    for (int j = 0; j < 8; ++j) {
        f0[j] = bf2f((ushort)u0[j]); f1[j] = bf2f((ushort)u1[j]);
        f2[j] = bf2f((ushort)u2[j]); f3[j] = bf2f((ushort)u3[j]);
    }
    #pragma unroll
    for (int k = 0; k < KS; ++k) {
        float w0 = sw[k * RT + 0], w1 = sw[k * RT + 1];
        float w2 = sw[k * RT + 2], w3 = sw[k * RT + 3];
        ushort8 o;
        #pragma unroll
        for (int j = 0; j < 8; ++j)
            o[j] = f2bf(w0 * f0[j] + w1 * f1[j] + w2 * f2[j] + w3 * f3[j]);
        *(ushort8*)(mixb + (size_t)k * NN * HDIM + (size_t)n * HDIM + c8) = o;
    }
}

// ======================================================================
// bf16 MFMA GEMM (round-7/10 structure — proven best across r7-r12):
// C[m][n] = sum_k A[m][k]*B[n][k]; 128x128 tile, BK=32, 4 waves x (64x64).
// Single-buffer staging via global_load_lds (16B/lane, linear LDS dest)
// with XOR-swizzled SOURCE cols; LDS reads apply the same XOR.
// swap2: grid is (ny*nz, gx) with (y,z) on the FAST axis so all blocks
// sharing an A row-panel are dispatched consecutively -> A-panel stays
// hot in L2/L3 (kills the 12x A over-fetch in the batched QKV GEMM).
// Epilogue: +bias, relu, optional gate -> LDS repack (swizzled,
// conflict-free) -> coalesced ushort8 stores. Output bf16. K%32==0.
// ======================================================================
__global__ __launch_bounds__(256) void gemm_bf16_nt(
    const ushort* __restrict__ A, const ushort* __restrict__ B,
    const float* __restrict__ bias, const float* __restrict__ gatep,
    ushort* __restrict__ Cout,
    int M, int Kd, int lda, int ldb, int ldc,
    long long sA, long long sB, long long sBias, long long sC,
    int relu, int gate_mode, int swap2)
{
    int bxi, byi, z;
    if (swap2) {   // grid (ny*nz, gx): blockIdx.x = y + 2*z (ny==2), blockIdx.y = row tile
        bxi = blockIdx.y;
        byi = blockIdx.x & 1;
        z   = blockIdx.x >> 1;
    } else {
        bxi = blockIdx.x;
        byi = blockIdx.y;
        z   = blockIdx.z;
    }
    A += (size_t)z * sA;
    B += (size_t)z * sB;
    if (bias) bias += (size_t)z * sBias;

    __shared__ ushort smem[128 * 128];   // 32 KB: As(8K)+Bs(8K) in loop; C-tile after
    ushort* As = smem;
    ushort* Bs = smem + 4096;

    const int tid  = threadIdx.x;
    const int lane = tid & 63;
    const int wid  = tid >> 6;
    const int wr   = (wid >> 1) * 64;
    const int wc   = (wid & 1) * 64;
    const int bm   = bxi * 128;
    const int bn   = byi * 128;

    f32x4 acc[4][4];
    #pragma unroll
    for (int m = 0; m < 4; ++m)
        #pragma unroll
        for (int n = 0; n < 4; ++n)
            #pragma unroll
            for (int e = 0; e < 4; ++e) acc[m][n][e] = 0.f;

    const int r0    = lane & 15;
    const int slotq = lane >> 4;          // logical 16B k-slot (0..3)

    // staging geometry: chunk = 1KB = 16 rows x 64B; row/col fixed per lane
    const int srow0 = ((wid << 1) << 4) + (lane >> 2);       // chunk c=0 row
    const int scol0 = (((lane & 3) ^ ((srow0 >> 1) & 3)) << 3);
    const int srow1 = srow0 + 16;                            // chunk c=1 row
    const int scol1 = (((lane & 3) ^ ((srow1 >> 1) & 3)) << 3);
    const int ga0 = bm + srow0 < M ? bm + srow0 : M - 1;
    const int ga1 = bm + srow1 < M ? bm + srow1 : M - 1;

    for (int k0 = 0; k0 < Kd; k0 += 32) {
        gload_lds16(A + (size_t)ga0 * lda + k0 + scol0, &As[(wid << 1) * 512]);
        gload_lds16(A + (size_t)ga1 * lda + k0 + scol1, &As[((wid << 1) + 1) * 512]);
        gload_lds16(B + (size_t)(bn + srow0) * ldb + k0 + scol0, &Bs[(wid << 1) * 512]);
        gload_lds16(B + (size_t)(bn + srow1) * ldb + k0 + scol1, &Bs[((wid << 1) + 1) * 512]);
        __syncthreads();
        short8 a[4], b[4];
        #pragma unroll
        for (int m = 0; m < 4; ++m) {
            int rr = wr + m * 16 + r0;
            a[m] = *(const short8*)(&As[rr * 32 + ((slotq ^ ((rr >> 1) & 3)) << 3)]);
        }
        #pragma unroll
        for (int n = 0; n < 4; ++n) {
            int rr = wc + n * 16 + r0;
            b[n] = *(const short8*)(&Bs[rr * 32 + ((slotq ^ ((rr >> 1) & 3)) << 3)]);
        }
        #pragma unroll
        for (int m = 0; m < 4; ++m)
            #pragma unroll
            for (int n = 0; n < 4; ++n)
                acc[m][n] = __builtin_amdgcn_mfma_f32_16x16x32_bf16(a[m], b[n], acc[m][n], 0, 0, 0);
        __syncthreads();
    }

    // ---- epilogue: registers -> LDS (swizzled, conflict-free) ----
    const int cr = (lane >> 4) * 4;
    const int cc = lane & 15;
    #pragma unroll
    for (int m = 0; m < 4; ++m) {
        #pragma unroll
        for (int j = 0; j < 4; ++j) {
            int row  = wr + m * 16 + cr + j;
            int grow = bm + row;
            float g = 1.0f;
            if (gate_mode) g = (grow < M) ? gatep[(size_t)grow * KS + z] : 0.f;
            int sw = ((row >> 2) & 3) << 5;
            #pragma unroll
            for (int n = 0; n < 4; ++n) {
                int col = wc + n * 16 + cc;
                float v = acc[m][n][j];
                if (bias) v += bias[bn + col];
                if (relu) v = fmaxf(v, 0.f);
                v *= g;
                *(ushort*)((char*)smem + row * 256 + ((col * 2) ^ sw)) = f2bf(v);
            }
        }
    }
    __syncthreads();
    // ---- LDS -> global, fully coalesced 16B stores ----
    #pragma unroll
    for (int it = 0; it < 8; ++it) {
        int row  = it * 16 + (tid >> 4);
        int grow = bm + row;
        int sw   = ((row >> 2) & 3) << 5;
        ushort8 vv = *(const ushort8*)((const char*)smem + row * 256 + (((tid & 15) * 16) ^ sw));
        if (grow < M)
            *(ushort8*)(Cout + (size_t)z * sC + (size_t)grow * ldc + bn + (tid & 15) * 8) = vv;
    }
}

// gate: logits = hid @ w2.T + b2 ; softmax over K. One wave per node. hid bf16.
__global__ __launch_bounds__(256) void gate_kernel(
    const ushort* __restrict__ hid, const float* __restrict__ w2,
    const float* __restrict__ b2, float* __restrict__ gate)
{
    int wid = threadIdx.x >> 6, lane = threadIdx.x & 63;
    int n = blockIdx.x * 4 + wid;
    if (n >= NN) return;
    ushort4 h4 = *(const ushort4*)(hid + (size_t)n * HDIM + lane * 4);
    float hx = bf2f(h4.x), hy = bf2f(h4.y), hz = bf2f(h4.z), hw = bf2f(h4.w);
    float lg[KS];
    #pragma unroll
    for (int k = 0; k < KS; ++k) {
        const float4 wv = *(const float4*)(w2 + k * HDIM + lane * 4);
        float p = hx * wv.x + hy * wv.y + hz * wv.z + hw * wv.w;
        #pragma unroll
        for (int m = 1; m < 64; m <<= 1) p += __shfl_xor(p, m);
        lg[k] = p + b2[k];
    }
    float m = lg[0];
    #pragma unroll
    for (int k = 1; k < KS; ++k) m = fmaxf(m, lg[k]);
    float ssum = 0.f;
    #pragma unroll
    for (int k = 0; k < KS; ++k) ssum += __expf(lg[k] - m);
    float inv = 1.0f / ssum;
    #pragma unroll
    for (int k = 0; k < KS; ++k)
        if (lane == k) gate[(size_t)n * KS + k] = __expf(lg[k] - m) * inv;
}

// residual + layernorm. One wave per node. hnew bf16.
__global__ __launch_bounds__(256) void ln_kernel(
    const float* __restrict__ h, const ushort* __restrict__ hnew,
    const float* __restrict__ gamma, const float* __restrict__ beta,
    float* __restrict__ out)
{
    int wid = threadIdx.x >> 6, lane = threadIdx.x & 63;
    int n = blockIdx.x * 4 + wid;
    if (n >= NN) return;
    size_t off = (size_t)n * HDIM + lane * 4;
    const float4 a = *(const float4*)(h + off);
    ushort4 b4 = *(const ushort4*)(hnew + off);
    float4 x = make_float4(a.x + bf2f(b4.x), a.y + bf2f(b4.y),
                           a.z + bf2f(b4.z), a.w + bf2f(b4.w));
    float s1 = x.x + x.y + x.z + x.w;
    float s2 = x.x * x.x + x.y * x.y + x.z * x.z + x.w * x.w;
    #pragma unroll
    for (int m = 1; m < 64; m <<= 1) { s1 += __shfl_xor(s1, m); s2 += __shfl_xor(s2, m); }
    float mu = s1 * (1.0f / HDIM);
    float var = s2 * (1.0f / HDIM) - mu * mu;
    float inv = rsqrtf(var + LN_EPS);
    const float4 g  = *(const float4*)(gamma + lane * 4);
    const float4 be = *(const float4*)(beta + lane * 4);
    float4 o;
    o.x = (x.x - mu) * inv * g.x + be.x;
    o.y = (x.y - mu) * inv * g.y + be.y;
    o.z = (x.z - mu) * inv * g.z + be.z;
    o.w = (x.w - mu) * inv * g.w + be.w;
    *(float4*)(out + off) = o;
}

extern "C" void kernel_launch(void* const* d_in, const int* in_sizes, int n_in,
                              void* d_out, int out_size, void* d_ws, size_t ws_size,
                              hipStream_t stream) {
    const float* h          = (const float*)d_in[0];
    const int*   edge_index = (const int*)d_in[1];
    const int*   edge_type  = (const int*)d_in[2];
    const float* W_q        = (const float*)d_in[3];
    const float* W_k        = (const float*)d_in[4];
    const float* W_v        = (const float*)d_in[5];
    const float* mlp_w1     = (const float*)d_in[6];
    const float* mlp_b1     = (const float*)d_in[7];
    const float* mlp_w2     = (const float*)d_in[8];
    const float* mlp_b2     = (const float*)d_in[9];
    const float* sym_logits = (const float*)d_in[10];
    const float* W_sym      = (const float*)d_in[11];
    const float* b_sym      = (const float*)d_in[12];
    const float* W_cross    = (const float*)d_in[13];
    const float* b_cross    = (const float*)d_in[14];
    const float* ln_gamma   = (const float*)d_in[15];
    const float* ln_beta    = (const float*)d_in[16];
    float* out = (float*)d_out;
    char*  ws  = (char*)d_ws;

    ushort* qkv    = (ushort*)(ws + OFFB_QKV);
    ushort* mixb   = (ushort*)(ws + OFFB_MIX);
    ushort* hnew   = (ushort*)(ws + OFFB_HNEW);
    ushort* catb   = (ushort*)(ws + OFFB_CATB);
    ushort* hid    = (ushort*)(ws + OFFB_HID);
    ushort* aggb   = (ushort*)(ws + OFFB_AGGB);
    ushort* hb     = (ushort*)(ws + OFFB_HB);
    float*  gate   = (float*)(ws + OFFB_GATE);
    ushort* wqkvb  = (ushort*)(ws + OFFB_WQKV);
    ushort* w1b    = (ushort*)(ws + OFFB_W1);
    ushort* wsymb  = (ushort*)(ws + OFFB_WSYM);
    ushort* wxb    = (ushort*)(ws + OFFB_WX);
    float*  symw   = (float*)(ws + OFFB_SYMW);
    int*    cnt    = (int*)(ws + OFFB_CNT);
    int*    rp     = (int*)(ws + OFFB_RP);
    int*    bsum   = (int*)(ws + OFFB_BSUM);
    int*    cursor = (int*)(ws + OFFB_CUR);
    int*    esrc   = (int*)(ws + OFFB_ESRC);

    const long long sRHH = (long long)RT * HDIM * HDIM;   // per-mat weight stride
    const long long sNH  = (long long)NN * HDIM;          // per-z output stride

    // ---- conversions ----
    cvt_bf16_kernel<<<5000, 256, 0, stream>>>(h, hb, NN * HDIM / 4);
    cvt_bf16_kernel<<<256, 256, 0, stream>>>(W_q, wqkvb,            RT * HDIM * HDIM / 4);
    cvt_bf16_kernel<<<256, 256, 0, stream>>>(W_k, wqkvb + sRHH,     RT * HDIM * HDIM / 4);
    cvt_bf16_kernel<<<256, 256, 0, stream>>>(W_v, wqkvb + 2 * sRHH, RT * HDIM * HDIM / 4);
    cvt_bf16_kernel<<<64, 256, 0, stream>>>(mlp_w1, w1b, HDIM * HDIM / 4);
    cvt_bf16_kernel<<<512, 256, 0, stream>>>(W_sym, wsymb, KS * HDIM * HDIM / 4);
    cvt_bf16_kernel<<<512, 256, 0, stream>>>(W_cross, wxb, HDIM * KS * HDIM / 4);
    symw_kernel<<<1, 64, 0, stream>>>(sym_logits, symw);

    // ---- routing MLP -> gate ----
    gemm_bf16_nt<<<dim3(157, 2, 1), 256, 0, stream>>>(hb, w1b, mlp_b1, nullptr, hid,
        NN, HDIM, HDIM, HDIM, HDIM, 0, 0, 0, 0, 1, 0, 0);
    gate_kernel<<<NN / 4, 256, 0, stream>>>(hid, mlp_w2, mlp_b2, gate);

    // ---- CSR build over seg = t*N + dst ----
    hipMemsetAsync(cnt, 0, NSEG * sizeof(int), stream);
    hist_kernel<<<NE / 256, 256, 0, stream>>>(edge_index, edge_type, cnt);
    scan1_kernel<<<79, 256, 0, stream>>>(cnt, rp, bsum);
    scan2_kernel<<<1, 256, 0, stream>>>(bsum, 79);
    scan3_kernel<<<313, 256, 0, stream>>>(rp, bsum, cursor);
    reorder_kernel<<<NE / 256, 256, 0, stream>>>(edge_index, edge_type, cursor, esrc);

    // ---- QKV batched GEMM (z = mat*4+t), A-panel-sharing dispatch order:
    //      grid (24, 157): 24 consecutive blocks share one 64KB A-panel ----
    gemm_bf16_nt<<<dim3(24, 157, 1), 256, 0, stream>>>(hb, wqkvb, nullptr, nullptr, qkv,
        NN, HDIM, HDIM, HDIM, HDIM, 0, (long long)HDIM * HDIM, 0, sNH, 0, 0, 1);

    // ---- gather attention: one wave per segment, single pass, dual chains ----
    attn_kernel<<<NSEG / 4, 256, 0, stream>>>(qkv, esrc, rp, aggb);

    // ---- symw mix: mixb (K,N,H) bf16, over dead QKV ----
    mix_kernel<<<NN * HDIM / 8 / 256, 256, 0, stream>>>(aggb, symw, mixb);

    // ---- symptom GEMM, z=k: catb[n, z*256+col] = relu(mixb_z @ Wsym_z.T + b_sym_z)*gate ----
    gemm_bf16_nt<<<dim3(157, 2, KS), 256, 0, stream>>>(mixb, wsymb, b_sym, gate, catb,
        NN, HDIM, HDIM, HDIM, KS * HDIM,
        sNH, (long long)HDIM * HDIM, HDIM, HDIM, 1, 1, 0);

    // ---- cross GEMM: hnew = relu(catb @ W_cross.T + b_cross), bf16 out ----
    gemm_bf16_nt<<<dim3(157, 2, 1), 256, 0, stream>>>(catb, wxb, b_cross, nullptr, hnew,
        NN, KS * HDIM, KS * HDIM, KS * HDIM, HDIM, 0, 0, 0, 0, 1, 0, 0);

    // ---- residual + layernorm ----
    ln_kernel<<<NN / 4, 256, 0, stream>>>(h, hnew, ln_gamma, ln_beta, out);
}

// Round 14
// 375.047 us; speedup vs baseline: 1.1941x; 1.0269x over previous
//
#include <hip/hip_runtime.h>

// ---- problem constants ----
#define NN     20000   // nodes
#define HDIM   256     // hidden
#define RT     4       // relation types
#define KS     8       // symptom channels
#define NHEAD  4
#define HDHEAD 64
#define NE     320000  // edges
#define NSEG   (RT * NN)   // 80000 segments
#define LN_EPS 1e-5f
// SCALE = sqrt(64) = 8

typedef __attribute__((ext_vector_type(8))) short short8;            // 8 bf16 = 4 VGPRs
typedef __attribute__((ext_vector_type(8))) unsigned short ushort8;  // 8 bf16
typedef __attribute__((ext_vector_type(4))) float f32x4;

// ---- workspace layout (BYTE offsets), liveness-reused ----
static constexpr size_t OFFB_QKV  = 0;
static constexpr size_t OFFB_HNEW = 0;           // bf16 (N,H) 10.24M (over dead QKV)
static constexpr size_t OFFB_CATB = 81920000;    // 81.92M bf16 (N,K*H)
static constexpr size_t OFFB_HID  = 122880000;   // bf16 (N,H) 10.24M (phase 1 only)
static constexpr size_t OFFB_AGGB = 122880000;   // bf16 (N,R*H) 40.96M
static constexpr size_t OFFB_HB   = 163840000;   // bf16 h (N,H) 10.24M
static constexpr size_t OFFB_GATE = 174080000;   // fp32 (N,KS) 640K
static constexpr size_t OFFB_WQKV = 174720000;   // bf16 [3][RT][H][H] 1,572,864
static constexpr size_t OFFB_W1   = 176292864;   // bf16 (H,H) 131,072
static constexpr size_t OFFB_WSYM = 176423936;   // bf16 (K,H,H) 1,048,576
static constexpr size_t OFFB_WX   = 177472512;   // bf16 (H,K*H) 1,048,576
static constexpr size_t OFFB_SYMW = 178521088;   // fp32 (K,R) pad 256
static constexpr size_t OFFB_CNT  = 178521344;   // int [NSEG] 320,000
static constexpr size_t OFFB_RP   = 178841344;   // int [NSEG+1] pad 320,016
static constexpr size_t OFFB_BSUM = 179161360;   // int [128] 512
static constexpr size_t OFFB_CUR  = 179161872;   // int [NSEG] 320,000
static constexpr size_t OFFB_ESRC = 179481872;   // int [NE] 1,280,000 (src id per CSR slot)
// end = 180,761,872 B (~172.4 MiB)

// ---- helpers ----
__device__ inline ushort f2bf(float f) {
    unsigned u = __float_as_uint(f);
    unsigned r = (u + 0x7FFFu + ((u >> 16) & 1u)) >> 16;
    return (ushort)r;
}
__device__ inline float bf2f(ushort u) { return __uint_as_float(((unsigned)u) << 16); }

// direct global->LDS DMA, 16B per lane. lds dest = wave-uniform base + lane*16.
__device__ inline void gload_lds16(const ushort* g, ushort* l) {
    __builtin_amdgcn_global_load_lds(
        (const __attribute__((address_space(1))) void*)g,
        (__attribute__((address_space(3))) void*)l, 16, 0, 0);
}

// ======================================================================
// f32 -> bf16 convert (4 elems/thread)
// ======================================================================
__global__ __launch_bounds__(256) void cvt_bf16_kernel(
    const float* __restrict__ in, ushort* __restrict__ out, int n4)
{
    int g = blockIdx.x * 256 + threadIdx.x;
    if (g >= n4) return;
    float4 v = *(const float4*)(in + (size_t)g * 4);
    ushort4 o;
    o.x = f2bf(v.x); o.y = f2bf(v.y); o.z = f2bf(v.z); o.w = f2bf(v.w);
    *(ushort4*)(out + (size_t)g * 4) = o;
}

// softmax over R of sym_edge_logits rows -> symw (K x R)
__global__ void symw_kernel(const float* __restrict__ logits, float* __restrict__ symw)
{
    int k = threadIdx.x;
    if (k >= KS) return;
    float v[RT]; float m = -1e30f;
    #pragma unroll
    for (int r = 0; r < RT; ++r) { v[r] = logits[k * RT + r]; m = fmaxf(m, v[r]); }
    float ssum = 0.f;
    #pragma unroll
    for (int r = 0; r < RT; ++r) { v[r] = __expf(v[r] - m); ssum += v[r]; }
    #pragma unroll
    for (int r = 0; r < RT; ++r) symw[k * RT + r] = v[r] / ssum;
}

// ======================================================================
// CSR build: histogram -> 2-level exclusive scan -> reorder
// ======================================================================
__global__ __launch_bounds__(256) void hist_kernel(
    const int* __restrict__ edge_index, const int* __restrict__ edge_type,
    int* __restrict__ cnt)
{
    int e = blockIdx.x * 256 + threadIdx.x;
    if (e >= NE) return;
    int seg = edge_type[e] * NN + edge_index[NE + e];
    atomicAdd(&cnt[seg], 1);
}

__global__ __launch_bounds__(256) void scan1_kernel(
    const int* __restrict__ cnt, int* __restrict__ rp, int* __restrict__ bsum)
{
    __shared__ int sh[256];
    int t = threadIdx.x;
    int base = blockIdx.x * 1024 + t * 4;
    int a0 = (base + 0 < NSEG) ? cnt[base + 0] : 0;
    int a1 = (base + 1 < NSEG) ? cnt[base + 1] : 0;
    int a2 = (base + 2 < NSEG) ? cnt[base + 2] : 0;
    int a3 = (base + 3 < NSEG) ? cnt[base + 3] : 0;
    int s = a0 + a1 + a2 + a3;
    sh[t] = s;
    __syncthreads();
    for (int off = 1; off < 256; off <<= 1) {
        int v = (t >= off) ? sh[t - off] : 0;
        __syncthreads();
        sh[t] += v;
        __syncthreads();
    }
    int excl = sh[t] - s;
    if (t == 255) bsum[blockIdx.x] = sh[255];
    if (base + 0 < NSEG) rp[base + 0] = excl;
    if (base + 1 < NSEG) rp[base + 1] = excl + a0;
    if (base + 2 < NSEG) rp[base + 2] = excl + a0 + a1;
    if (base + 3 < NSEG) rp[base + 3] = excl + a0 + a1 + a2;
}

__global__ __launch_bounds__(256) void scan2_kernel(int* __restrict__ bsum, int nb)
{
    __shared__ int sh[256];
    int t = threadIdx.x;
    int v = (t < nb) ? bsum[t] : 0;
    sh[t] = v;
    __syncthreads();
    for (int off = 1; off < 256; off <<= 1) {
        int u = (t >= off) ? sh[t - off] : 0;
        __syncthreads();
        sh[t] += u;
        __syncthreads();
    }
    if (t < nb) bsum[t] = sh[t] - v;   // exclusive
}

__global__ __launch_bounds__(256) void scan3_kernel(
    int* __restrict__ rp, const int* __restrict__ bsum, int* __restrict__ cursor)
{
    int i = blockIdx.x * 256 + threadIdx.x;
    if (i == 0) rp[NSEG] = NE;
    if (i >= NSEG) return;
    int v = rp[i] + bsum[i >> 10];
    rp[i] = v;
    cursor[i] = v;
}

// store src node id directly into CSR slot (kills one indirection in attn)
__global__ __launch_bounds__(256) void reorder_kernel(
    const int* __restrict__ edge_index, const int* __restrict__ edge_type,
    int* __restrict__ cursor, int* __restrict__ esrc)
{
    int e = blockIdx.x * 256 + threadIdx.x;
    if (e >= NE) return;
    int seg = edge_type[e] * NN + edge_index[NE + e];
    int pos = atomicAdd(&cursor[seg], 1);
    esrc[pos] = edge_index[e];
}

// ======================================================================
// Gather attention: ONE WAVE per segment, all 4 heads at once. Single
// pass, online softmax, 2-way unrolled dual accumulator chains.
// ======================================================================
__global__ __launch_bounds__(256) void attn_kernel(
    const ushort* __restrict__ qkv, const int* __restrict__ esrc,
    const int* __restrict__ rp, ushort* __restrict__ aggb)
{
    int seg  = blockIdx.x * 4 + (threadIdx.x >> 6);   // 4 waves/block, grid exact
    int lane = threadIdx.x & 63;
    int t = seg / NN;
    int d = seg - t * NN;
    ushort* outp = aggb + (size_t)d * (RT * HDIM) + t * HDIM + lane * 4;

    int begin = rp[seg], end = rp[seg + 1];
    if (begin == end) {               // empty segment -> zeros (matches segment_sum)
        ushort4 z; z.x = 0; z.y = 0; z.z = 0; z.w = 0;
        *(ushort4*)outp = z;
        return;
    }

    const size_t sMat = (size_t)RT * NN * HDIM;
    const ushort* Kbase = qkv + sMat     + (size_t)t * NN * HDIM + lane * 4;
    const ushort* Vbase = qkv + 2 * sMat + (size_t)t * NN * HDIM + lane * 4;

    ushort4 q4 = *(const ushort4*)(qkv + ((size_t)t * NN + d) * HDIM + lane * 4);
    float qx = bf2f(q4.x), qy = bf2f(q4.y), qz = bf2f(q4.z), qw = bf2f(q4.w);

    float mx0 = -1e30f, den0 = 0.f, a00 = 0.f, a01 = 0.f, a02 = 0.f, a03 = 0.f;
    float mx1 = -1e30f, den1 = 0.f, a10 = 0.f, a11 = 0.f, a12 = 0.f, a13 = 0.f;

    int p = begin;
    for (; p + 2 <= end; p += 2) {
        int s0 = esrc[p];
        int s1 = esrc[p + 1];
        ushort4 k0 = *(const ushort4*)(Kbase + (size_t)s0 * HDIM);
        ushort4 k1 = *(const ushort4*)(Kbase + (size_t)s1 * HDIM);
        ushort4 v0 = *(const ushort4*)(Vbase + (size_t)s0 * HDIM);
        ushort4 v1 = *(const ushort4*)(Vbase + (size_t)s1 * HDIM);
        float p0 = qx * bf2f(k0.x) + qy * bf2f(k0.y) + qz * bf2f(k0.z) + qw * bf2f(k0.w);
        float p1 = qx * bf2f(k1.x) + qy * bf2f(k1.y) + qz * bf2f(k1.z) + qw * bf2f(k1.w);
        p0 += __shfl_xor(p0, 1); p1 += __shfl_xor(p1, 1);
        p0 += __shfl_xor(p0, 2); p1 += __shfl_xor(p1, 2);
        p0 += __shfl_xor(p0, 4); p1 += __shfl_xor(p1, 4);
        p0 += __shfl_xor(p0, 8); p1 += __shfl_xor(p1, 8);
        p0 *= 0.125f;            p1 *= 0.125f;
        float nm0 = fmaxf(mx0, p0),      nm1 = fmaxf(mx1, p1);
        float c0  = __expf(mx0 - nm0),   c1  = __expf(mx1 - nm1);
        float w0  = __expf(p0 - nm0),    w1  = __expf(p1 - nm1);
        den0 = den0 * c0 + w0;           den1 = den1 * c1 + w1;
        a00 = a00 * c0 + w0 * bf2f(v0.x); a10 = a10 * c1 + w1 * bf2f(v1.x);
        a01 = a01 * c0 + w0 * bf2f(v0.y); a11 = a11 * c1 + w1 * bf2f(v1.y);
        a02 = a02 * c0 + w0 * bf2f(v0.z); a12 = a12 * c1 + w1 * bf2f(v1.z);
        a03 = a03 * c0 + w0 * bf2f(v0.w); a13 = a13 * c1 + w1 * bf2f(v1.w);
        mx0 = nm0;                        mx1 = nm1;
    }
    if (p < end) {   // odd tail -> chain 0
        int s0 = esrc[p];
        ushort4 k0 = *(const ushort4*)(Kbase + (size_t)s0 * HDIM);
        ushort4 v0 = *(const ushort4*)(Vbase + (size_t)s0 * HDIM);
        float p0 = qx * bf2f(k0.x) + qy * bf2f(k0.y) + qz * bf2f(k0.z) + qw * bf2f(k0.w);
        p0 += __shfl_xor(p0, 1); p0 += __shfl_xor(p0, 2);
        p0 += __shfl_xor(p0, 4); p0 += __shfl_xor(p0, 8);
        p0 *= 0.125f;
        float nm0 = fmaxf(mx0, p0);
        float c0  = __expf(mx0 - nm0);
        float w0  = __expf(p0 - nm0);
        den0 = den0 * c0 + w0;
        a00 = a00 * c0 + w0 * bf2f(v0.x);
        a01 = a01 * c0 + w0 * bf2f(v0.y);
        a02 = a02 * c0 + w0 * bf2f(v0.z);
        a03 = a03 * c0 + w0 * bf2f(v0.w);
        mx0 = nm0;
    }
    // merge the two chains (chain1 empty -> c1 = exp(-1e30-m) = 0)
    float m  = fmaxf(mx0, mx1);
    float c0 = __expf(mx0 - m), c1 = __expf(mx1 - m);
    float den = den0 * c0 + den1 * c1;
    float inv = 1.0f / den;
    ushort4 o;
    o.x = f2bf((a00 * c0 + a10 * c1) * inv);
    o.y = f2bf((a01 * c0 + a11 * c1) * inv);
    o.z = f2bf((a02 * c0 + a12 * c1) * inv);
    o.w = f2bf((a03 * c0 + a13 * c1) * inv);
    *(ushort4*)outp = o;
}

// ======================================================================
// bf16 MFMA GEMM (round-7/13 structure — proven best):
// 128x128 tile, BK=32, single-buffer gload_lds staging, swizzled both
// sides; LDS-repack coalesced epilogue; swap2 grid reorder option.
// ======================================================================
__global__ __launch_bounds__(256) void gemm_bf16_nt(
    const ushort* __restrict__ A, const ushort* __restrict__ B,
    const float* __restrict__ bias, const float* __restrict__ gatep,
    ushort* __restrict__ Cout,
    int M, int Kd, int lda, int ldb, int ldc,
    long long sA, long long sB, long long sBias, long long sC,
    int relu, int gate_mode, int swap2)
{
    int bxi, byi, z;
    if (swap2) {   // grid (ny*nz, gx): blockIdx.x = y + 2*z (ny==2), blockIdx.y = row tile
        bxi = blockIdx.y;
        byi = blockIdx.x & 1;
        z   = blockIdx.x >> 1;
    } else {
        bxi = blockIdx.x;
        byi = blockIdx.y;
        z   = blockIdx.z;
    }
    A += (size_t)z * sA;
    B += (size_t)z * sB;
    if (bias) bias += (size_t)z * sBias;

    __shared__ ushort smem[128 * 128];   // 32 KB: As(8K)+Bs(8K) in loop; C-tile after
    ushort* As = smem;
    ushort* Bs = smem + 4096;

    const int tid  = threadIdx.x;
    const int lane = tid & 63;
    const int wid  = tid >> 6;
    const int wr   = (wid >> 1) * 64;
    const int wc   = (wid & 1) * 64;
    const int bm   = bxi * 128;
    const int bn   = byi * 128;

    f32x4 acc[4][4];
    #pragma unroll
    for (int m = 0; m < 4; ++m)
        #pragma unroll
        for (int n = 0; n < 4; ++n)
            #pragma unroll
            for (int e = 0; e < 4; ++e) acc[m][n][e] = 0.f;

    const int r0    = lane & 15;
    const int slotq = lane >> 4;          // logical 16B k-slot (0..3)

    const int srow0 = ((wid << 1) << 4) + (lane >> 2);       // chunk c=0 row
    const int scol0 = (((lane & 3) ^ ((srow0 >> 1) & 3)) << 3);
    const int srow1 = srow0 + 16;                            // chunk c=1 row
    const int scol1 = (((lane & 3) ^ ((srow1 >> 1) & 3)) << 3);
    const int ga0 = bm + srow0 < M ? bm + srow0 : M - 1;
    const int ga1 = bm + srow1 < M ? bm + srow1 : M - 1;

    for (int k0 = 0; k0 < Kd; k0 += 32) {
        gload_lds16(A + (size_t)ga0 * lda + k0 + scol0, &As[(wid << 1) * 512]);
        gload_lds16(A + (size_t)ga1 * lda + k0 + scol1, &As[((wid << 1) + 1) * 512]);
        gload_lds16(B + (size_t)(bn + srow0) * ldb + k0 + scol0, &Bs[(wid << 1) * 512]);
        gload_lds16(B + (size_t)(bn + srow1) * ldb + k0 + scol1, &Bs[((wid << 1) + 1) * 512]);
        __syncthreads();
        short8 a[4], b[4];
        #pragma unroll
        for (int m = 0; m < 4; ++m) {
            int rr = wr + m * 16 + r0;
            a[m] = *(const short8*)(&As[rr * 32 + ((slotq ^ ((rr >> 1) & 3)) << 3)]);
        }
        #pragma unroll
        for (int n = 0; n < 4; ++n) {
            int rr = wc + n * 16 + r0;
            b[n] = *(const short8*)(&Bs[rr * 32 + ((slotq ^ ((rr >> 1) & 3)) << 3)]);
        }
        #pragma unroll
        for (int m = 0; m < 4; ++m)
            #pragma unroll
            for (int n = 0; n < 4; ++n)
                acc[m][n] = __builtin_amdgcn_mfma_f32_16x16x32_bf16(a[m], b[n], acc[m][n], 0, 0, 0);
        __syncthreads();
    }

    const int cr = (lane >> 4) * 4;
    const int cc = lane & 15;
    #pragma unroll
    for (int m = 0; m < 4; ++m) {
        #pragma unroll
        for (int j = 0; j < 4; ++j) {
            int row  = wr + m * 16 + cr + j;
            int grow = bm + row;
            float g = 1.0f;
            if (gate_mode) g = (grow < M) ? gatep[(size_t)grow * KS + z] : 0.f;
            int sw = ((row >> 2) & 3) << 5;
            #pragma unroll
            for (int n = 0; n < 4; ++n) {
                int col = wc + n * 16 + cc;
                float v = acc[m][n][j];
                if (bias) v += bias[bn + col];
                if (relu) v = fmaxf(v, 0.f);
                v *= g;
                *(ushort*)((char*)smem + row * 256 + ((col * 2) ^ sw)) = f2bf(v);
            }
        }
    }
    __syncthreads();
    #pragma unroll
    for (int it = 0; it < 8; ++it) {
        int row  = it * 16 + (tid >> 4);
        int grow = bm + row;
        int sw   = ((row >> 2) & 3) << 5;
        ushort8 vv = *(const ushort8*)((const char*)smem + row * 256 + (((tid & 15) * 16) ^ sw));
        if (grow < M)
            *(ushort8*)(Cout + (size_t)z * sC + (size_t)grow * ldc + bn + (tid & 15) * 8) = vv;
    }
}

// ======================================================================
// Fused symw-mix + symptom GEMM (replaces mix_kernel + symptom dispatch).
// A_virt[n][i] = sum_r symw[z][r]*aggb[n][r*256+i] (== mix_kernel math).
// Grid (16, 157): (y,z) on FAST axis -> 16 consecutive blocks share one
// 256KB aggb row-panel (L2-resident; fixes r3's 589MB FETCH). A is
// reg-staged + swizzled ds_write (layout == read side); B via gload_lds.
// K-loop sync structure identical to gemm_bf16_nt.
// ======================================================================
__global__ __launch_bounds__(256) void gemm_amix(
    const ushort* __restrict__ aggb, const ushort* __restrict__ Wsym,
    const float* __restrict__ b_sym, const float* __restrict__ gatep,
    const float* __restrict__ symw, ushort* __restrict__ catb, int M)
{
    const int y  = blockIdx.x & 1;
    const int z  = blockIdx.x >> 1;
    const int bm = blockIdx.y * 128;
    const int bn = y * 128;
    const ushort* B = Wsym + (size_t)z * HDIM * HDIM;
    const float sw0 = symw[z * RT + 0], sw1 = symw[z * RT + 1];
    const float sw2 = symw[z * RT + 2], sw3 = symw[z * RT + 3];

    __shared__ ushort smem[128 * 128];
    ushort* As = smem;
    ushort* Bs = smem + 4096;

    const int tid  = threadIdx.x;
    const int lane = tid & 63;
    const int wid  = tid >> 6;
    const int wr   = (wid >> 1) * 64;
    const int wc   = (wid & 1) * 64;

    f32x4 acc[4][4];
    #pragma unroll
    for (int m = 0; m < 4; ++m)
        #pragma unroll
        for (int n = 0; n < 4; ++n)
            #pragma unroll
            for (int e = 0; e < 4; ++e) acc[m][n][e] = 0.f;

    const int r0    = lane & 15;
    const int slotq = lane >> 4;

    // B staging (gload_lds, same geometry as gemm_bf16_nt)
    const int srow0 = ((wid << 1) << 4) + (lane >> 2);
    const int scol0 = (((lane & 3) ^ ((srow0 >> 1) & 3)) << 3);
    const int srow1 = srow0 + 16;
    const int scol1 = (((lane & 3) ^ ((srow1 >> 1) & 3)) << 3);

    // A reg-staging: slots tid and tid+256 (slot = row*4 + sl)
    const int arow0 = tid >> 2,          asl = tid & 3;
    const int arow1 = arow0 + 64;
    const int gaa0 = (bm + arow0 < M) ? bm + arow0 : M - 1;
    const int gaa1 = (bm + arow1 < M) ? bm + arow1 : M - 1;
    const int aoff0 = arow0 * 32 + ((asl ^ ((arow0 >> 1) & 3)) << 3);
    const int aoff1 = arow1 * 32 + ((asl ^ ((arow1 >> 1) & 3)) << 3);

    for (int k0 = 0; k0 < HDIM; k0 += 32) {
        gload_lds16(B + (size_t)(bn + srow0) * HDIM + k0 + scol0, &Bs[(wid << 1) * 512]);
        gload_lds16(B + (size_t)(bn + srow1) * HDIM + k0 + scol1, &Bs[((wid << 1) + 1) * 512]);
        {
            const ushort* ab0 = aggb + (size_t)gaa0 * (RT * HDIM) + k0 + asl * 8;
            const ushort* ab1 = aggb + (size_t)gaa1 * (RT * HDIM) + k0 + asl * 8;
            ushort8 u00 = *(const ushort8*)(ab0);
            ushort8 u01 = *(const ushort8*)(ab0 + HDIM);
            ushort8 u02 = *(const ushort8*)(ab0 + 2 * HDIM);
            ushort8 u03 = *(const ushort8*)(ab0 + 3 * HDIM);
            ushort8 u10 = *(const ushort8*)(ab1);
            ushort8 u11 = *(const ushort8*)(ab1 + HDIM);
            ushort8 u12 = *(const ushort8*)(ab1 + 2 * HDIM);
            ushort8 u13 = *(const ushort8*)(ab1 + 3 * HDIM);
            ushort8 o0, o1;
            #pragma unroll
            for (int j = 0; j < 8; ++j) {
                o0[j] = f2bf(sw0 * bf2f((ushort)u00[j]) + sw1 * bf2f((ushort)u01[j]) +
                             sw2 * bf2f((ushort)u02[j]) + sw3 * bf2f((ushort)u03[j]));
                o1[j] = f2bf(sw0 * bf2f((ushort)u10[j]) + sw1 * bf2f((ushort)u11[j]) +
                             sw2 * bf2f((ushort)u12[j]) + sw3 * bf2f((ushort)u13[j]));
            }
            *(ushort8*)(&As[aoff0]) = o0;
            *(ushort8*)(&As[aoff1]) = o1;
        }
        __syncthreads();
        short8 a[4], b[4];
        #pragma unroll
        for (int m = 0; m < 4; ++m) {
            int rr = wr + m * 16 + r0;
            a[m] = *(const short8*)(&As[rr * 32 + ((slotq ^ ((rr >> 1) & 3)) << 3)]);
        }
        #pragma unroll
        for (int n = 0; n < 4; ++n) {
            int rr = wc + n * 16 + r0;
            b[n] = *(const short8*)(&Bs[rr * 32 + ((slotq ^ ((rr >> 1) & 3)) << 3)]);
        }
        #pragma unroll
        for (int m = 0; m < 4; ++m)
            #pragma unroll
            for (int n = 0; n < 4; ++n)
                acc[m][n] = __builtin_amdgcn_mfma_f32_16x16x32_bf16(a[m], b[n], acc[m][n], 0, 0, 0);
        __syncthreads();
    }

    const int cr = (lane >> 4) * 4;
    const int cc = lane & 15;
    #pragma unroll
    for (int m = 0; m < 4; ++m) {
        #pragma unroll
        for (int j = 0; j < 4; ++j) {
            int row  = wr + m * 16 + cr + j;
            int grow = bm + row;
            float g = (grow < M) ? gatep[(size_t)grow * KS + z] : 0.f;
            int sw = ((row >> 2) & 3) << 5;
            #pragma unroll
            for (int n = 0; n < 4; ++n) {
                int col = wc + n * 16 + cc;
                float v = acc[m][n][j] + b_sym[z * HDIM + bn + col];
                v = fmaxf(v, 0.f) * g;
                *(ushort*)((char*)smem + row * 256 + ((col * 2) ^ sw)) = f2bf(v);
            }
        }
    }
    __syncthreads();
    #pragma unroll
    for (int it = 0; it < 8; ++it) {
        int row  = it * 16 + (tid >> 4);
        int grow = bm + row;
        int sw   = ((row >> 2) & 3) << 5;
        ushort8 vv = *(const ushort8*)((const char*)smem + row * 256 + (((tid & 15) * 16) ^ sw));
        if (grow < M)
            *(ushort8*)(catb + (size_t)grow * (KS * HDIM) + z * HDIM + bn + (tid & 15) * 8) = vv;
    }
}

// gate: logits = hid @ w2.T + b2 ; softmax over K. One wave per node. hid bf16.
__global__ __launch_bounds__(256) void gate_kernel(
    const ushort* __restrict__ hid, const float* __restrict__ w2,
    const float* __restrict__ b2, float* __restrict__ gate)
{
    int wid = threadIdx.x >> 6, lane = threadIdx.x & 63;
    int n = blockIdx.x * 4 + wid;
    if (n >= NN) return;
    ushort4 h4 = *(const ushort4*)(hid + (size_t)n * HDIM + lane * 4);
    float hx = bf2f(h4.x), hy = bf2f(h4.y), hz = bf2f(h4.z), hw = bf2f(h4.w);
    float lg[KS];
    #pragma unroll
    for (int k = 0; k < KS; ++k) {
        const float4 wv = *(const float4*)(w2 + k * HDIM + lane * 4);
        float p = hx * wv.x + hy * wv.y + hz * wv.z + hw * wv.w;
        #pragma unroll
        for (int m = 1; m < 64; m <<= 1) p += __shfl_xor(p, m);
        lg[k] = p + b2[k];
    }
    float m = lg[0];
    #pragma unroll
    for (int k = 1; k < KS; ++k) m = fmaxf(m, lg[k]);
    float ssum = 0.f;
    #pragma unroll
    for (int k = 0; k < KS; ++k) ssum += __expf(lg[k] - m);
    float inv = 1.0f / ssum;
    #pragma unroll
    for (int k = 0; k < KS; ++k)
        if (lane == k) gate[(size_t)n * KS + k] = __expf(lg[k] - m) * inv;
}

// residual + layernorm. One wave per node. hnew bf16.
__global__ __launch_bounds__(256) void ln_kernel(
    const float* __restrict__ h, const ushort* __restrict__ hnew,
    const float* __restrict__ gamma, const float* __restrict__ beta,
    float* __restrict__ out)
{
    int wid = threadIdx.x >> 6, lane = threadIdx.x & 63;
    int n = blockIdx.x * 4 + wid;
    if (n >= NN) return;
    size_t off = (size_t)n * HDIM + lane * 4;
    const float4 a = *(const float4*)(h + off);
    ushort4 b4 = *(const ushort4*)(hnew + off);
    float4 x = make_float4(a.x + bf2f(b4.x), a.y + bf2f(b4.y),
                           a.z + bf2f(b4.z), a.w + bf2f(b4.w));
    float s1 = x.x + x.y + x.z + x.w;
    float s2 = x.x * x.x + x.y * x.y + x.z * x.z + x.w * x.w;
    #pragma unroll
    for (int m = 1; m < 64; m <<= 1) { s1 += __shfl_xor(s1, m); s2 += __shfl_xor(s2, m); }
    float mu = s1 * (1.0f / HDIM);
    float var = s2 * (1.0f / HDIM) - mu * mu;
    float inv = rsqrtf(var + LN_EPS);
    const float4 g  = *(const float4*)(gamma + lane * 4);
    const float4 be = *(const float4*)(beta + lane * 4);
    float4 o;
    o.x = (x.x - mu) * inv * g.x + be.x;
    o.y = (x.y - mu) * inv * g.y + be.y;
    o.z = (x.z - mu) * inv * g.z + be.z;
    o.w = (x.w - mu) * inv * g.w + be.w;
    *(float4*)(out + off) = o;
}

extern "C" void kernel_launch(void* const* d_in, const int* in_sizes, int n_in,
                              void* d_out, int out_size, void* d_ws, size_t ws_size,
                              hipStream_t stream) {
    const float* h          = (const float*)d_in[0];
    const int*   edge_index = (const int*)d_in[1];
    const int*   edge_type  = (const int*)d_in[2];
    const float* W_q        = (const float*)d_in[3];
    const float* W_k        = (const float*)d_in[4];
    const float* W_v        = (const float*)d_in[5];
    const float* mlp_w1     = (const float*)d_in[6];
    const float* mlp_b1     = (const float*)d_in[7];
    const float* mlp_w2     = (const float*)d_in[8];
    const float* mlp_b2     = (const float*)d_in[9];
    const float* sym_logits = (const float*)d_in[10];
    const float* W_sym      = (const float*)d_in[11];
    const float* b_sym      = (const float*)d_in[12];
    const float* W_cross    = (const float*)d_in[13];
    const float* b_cross    = (const float*)d_in[14];
    const float* ln_gamma   = (const float*)d_in[15];
    const float* ln_beta    = (const float*)d_in[16];
    float* out = (float*)d_out;
    char*  ws  = (char*)d_ws;

    ushort* qkv    = (ushort*)(ws + OFFB_QKV);
    ushort* hnew   = (ushort*)(ws + OFFB_HNEW);
    ushort* catb   = (ushort*)(ws + OFFB_CATB);
    ushort* hid    = (ushort*)(ws + OFFB_HID);
    ushort* aggb   = (ushort*)(ws + OFFB_AGGB);
    ushort* hb     = (ushort*)(ws + OFFB_HB);
    float*  gate   = (float*)(ws + OFFB_GATE);
    ushort* wqkvb  = (ushort*)(ws + OFFB_WQKV);
    ushort* w1b    = (ushort*)(ws + OFFB_W1);
    ushort* wsymb  = (ushort*)(ws + OFFB_WSYM);
    ushort* wxb    = (ushort*)(ws + OFFB_WX);
    float*  symw   = (float*)(ws + OFFB_SYMW);
    int*    cnt    = (int*)(ws + OFFB_CNT);
    int*    rp     = (int*)(ws + OFFB_RP);
    int*    bsum   = (int*)(ws + OFFB_BSUM);
    int*    cursor = (int*)(ws + OFFB_CUR);
    int*    esrc   = (int*)(ws + OFFB_ESRC);

    const long long sRHH = (long long)RT * HDIM * HDIM;   // per-mat weight stride
    const long long sNH  = (long long)NN * HDIM;          // per-z output stride

    // ---- conversions ----
    cvt_bf16_kernel<<<5000, 256, 0, stream>>>(h, hb, NN * HDIM / 4);
    cvt_bf16_kernel<<<256, 256, 0, stream>>>(W_q, wqkvb,            RT * HDIM * HDIM / 4);
    cvt_bf16_kernel<<<256, 256, 0, stream>>>(W_k, wqkvb + sRHH,     RT * HDIM * HDIM / 4);
    cvt_bf16_kernel<<<256, 256, 0, stream>>>(W_v, wqkvb + 2 * sRHH, RT * HDIM * HDIM / 4);
    cvt_bf16_kernel<<<64, 256, 0, stream>>>(mlp_w1, w1b, HDIM * HDIM / 4);
    cvt_bf16_kernel<<<512, 256, 0, stream>>>(W_sym, wsymb, KS * HDIM * HDIM / 4);
    cvt_bf16_kernel<<<512, 256, 0, stream>>>(W_cross, wxb, HDIM * KS * HDIM / 4);
    symw_kernel<<<1, 64, 0, stream>>>(sym_logits, symw);

    // ---- routing MLP -> gate ----
    gemm_bf16_nt<<<dim3(157, 2, 1), 256, 0, stream>>>(hb, w1b, mlp_b1, nullptr, hid,
        NN, HDIM, HDIM, HDIM, HDIM, 0, 0, 0, 0, 1, 0, 0);
    gate_kernel<<<NN / 4, 256, 0, stream>>>(hid, mlp_w2, mlp_b2, gate);

    // ---- CSR build over seg = t*N + dst ----
    hipMemsetAsync(cnt, 0, NSEG * sizeof(int), stream);
    hist_kernel<<<NE / 256, 256, 0, stream>>>(edge_index, edge_type, cnt);
    scan1_kernel<<<79, 256, 0, stream>>>(cnt, rp, bsum);
    scan2_kernel<<<1, 256, 0, stream>>>(bsum, 79);
    scan3_kernel<<<313, 256, 0, stream>>>(rp, bsum, cursor);
    reorder_kernel<<<NE / 256, 256, 0, stream>>>(edge_index, edge_type, cursor, esrc);

    // ---- QKV batched GEMM (z = mat*4+t), A-panel-sharing dispatch order ----
    gemm_bf16_nt<<<dim3(24, 157, 1), 256, 0, stream>>>(hb, wqkvb, nullptr, nullptr, qkv,
        NN, HDIM, HDIM, HDIM, HDIM, 0, (long long)HDIM * HDIM, 0, sNH, 0, 0, 1);

    // ---- gather attention: one wave per segment, single pass, dual chains ----
    attn_kernel<<<NSEG / 4, 256, 0, stream>>>(qkv, esrc, rp, aggb);

    // ---- FUSED symw-mix + symptom GEMM -> catb (N, K*H) ----
    gemm_amix<<<dim3(16, 157), 256, 0, stream>>>(aggb, wsymb, b_sym, gate, symw, catb, NN);

    // ---- cross GEMM: hnew = relu(catb @ W_cross.T + b_cross), bf16 out ----
    gemm_bf16_nt<<<dim3(157, 2, 1), 256, 0, stream>>>(catb, wxb, b_cross, nullptr, hnew,
        NN, KS * HDIM, KS * HDIM, KS * HDIM, HDIM, 0, 0, 0, 0, 1, 0, 0);

    // ---- residual + layernorm ----
    ln_kernel<<<NN / 4, 256, 0, stream>>>(h, hnew, ln_gamma, ln_beta, out);
}

// Round 15
// 362.501 us; speedup vs baseline: 1.2355x; 1.0346x over previous
//
#include <hip/hip_runtime.h>

// ---- problem constants ----
#define NN     20000   // nodes
#define HDIM   256     // hidden
#define RT     4       // relation types
#define KS     8       // symptom channels
#define NHEAD  4
#define HDHEAD 64
#define NE     320000  // edges
#define NSEG   (RT * NN)   // 80000 segments
#define LN_EPS 1e-5f
// SCALE = sqrt(64) = 8

typedef __attribute__((ext_vector_type(8))) short short8;            // 8 bf16 = 4 VGPRs
typedef __attribute__((ext_vector_type(8))) unsigned short ushort8;  // 8 bf16
typedef __attribute__((ext_vector_type(4))) float f32x4;

// ---- workspace layout (BYTE offsets), liveness-reused ----
static constexpr size_t OFFB_QKV  = 0;
static constexpr size_t OFFB_HNEW = 0;           // bf16 (N,H) 10.24M (over dead QKV)
static constexpr size_t OFFB_CATB = 81920000;    // 81.92M bf16 (N,K*H)
static constexpr size_t OFFB_HID  = 122880000;   // bf16 (N,H) = qkv plane 12 (contiguous!)
static constexpr size_t OFFB_AGGB = 133120000;   // bf16 (N,R*H) 40.96M, ends 174,080,000
static constexpr size_t OFFB_HB   = 174080000;   // bf16 h (N,H) 10.24M
static constexpr size_t OFFB_GATE = 184320000;   // fp32 (N,KS) 640K
static constexpr size_t OFFB_WQKV = 184960000;   // bf16 [3][RT][H][H] 1,572,864
static constexpr size_t OFFB_W1   = 186532864;   // bf16 (H,H) 131,072  (contiguous after WQKV)
static constexpr size_t OFFB_WSYM = 186663936;   // bf16 (K,H,H) 1,048,576
static constexpr size_t OFFB_WX   = 187712512;   // bf16 (H,K*H) 1,048,576
static constexpr size_t OFFB_SYMW = 188761088;   // fp32 (K,R) pad 256
static constexpr size_t OFFB_CNT  = 188761344;   // int [NSEG] 320,000
static constexpr size_t OFFB_RP   = 189081344;   // int [NSEG+1] pad 320,016
static constexpr size_t OFFB_BSUM = 189401360;   // int [128] 512
static constexpr size_t OFFB_CUR  = 189401872;   // int [NSEG] 320,000
static constexpr size_t OFFB_ESRC = 189721872;   // int [NE] 1,280,000
// end = 191,001,872 B (~182.2 MiB) -- known-good ws >= 197.7 MB (round-2 layout ran)

// ---- helpers ----
__device__ inline ushort f2bf(float f) {
    unsigned u = __float_as_uint(f);
    unsigned r = (u + 0x7FFFu + ((u >> 16) & 1u)) >> 16;
    return (ushort)r;
}
__device__ inline float bf2f(ushort u) { return __uint_as_float(((unsigned)u) << 16); }

// direct global->LDS DMA, 16B per lane. lds dest = wave-uniform base + lane*16.
__device__ inline void gload_lds16(const ushort* g, ushort* l) {
    __builtin_amdgcn_global_load_lds(
        (const __attribute__((address_space(1))) void*)g,
        (__attribute__((address_space(3))) void*)l, 16, 0, 0);
}

// ======================================================================
// f32 -> bf16 convert (4 elems/thread)
// ======================================================================
__global__ __launch_bounds__(256) void cvt_bf16_kernel(
    const float* __restrict__ in, ushort* __restrict__ out, int n4)
{
    int g = blockIdx.x * 256 + threadIdx.x;
    if (g >= n4) return;
    float4 v = *(const float4*)(in + (size_t)g * 4);
    ushort4 o;
    o.x = f2bf(v.x); o.y = f2bf(v.y); o.z = f2bf(v.z); o.w = f2bf(v.w);
    *(ushort4*)(out + (size_t)g * 4) = o;
}

// softmax over R of sym_edge_logits rows -> symw (K x R)
__global__ void symw_kernel(const float* __restrict__ logits, float* __restrict__ symw)
{
    int k = threadIdx.x;
    if (k >= KS) return;
    float v[RT]; float m = -1e30f;
    #pragma unroll
    for (int r = 0; r < RT; ++r) { v[r] = logits[k * RT + r]; m = fmaxf(m, v[r]); }
    float ssum = 0.f;
    #pragma unroll
    for (int r = 0; r < RT; ++r) { v[r] = __expf(v[r] - m); ssum += v[r]; }
    #pragma unroll
    for (int r = 0; r < RT; ++r) symw[k * RT + r] = v[r] / ssum;
}

// ======================================================================
// CSR build: histogram -> 2-level exclusive scan -> reorder
// ======================================================================
__global__ __launch_bounds__(256) void hist_kernel(
    const int* __restrict__ edge_index, const int* __restrict__ edge_type,
    int* __restrict__ cnt)
{
    int e = blockIdx.x * 256 + threadIdx.x;
    if (e >= NE) return;
    int seg = edge_type[e] * NN + edge_index[NE + e];
    atomicAdd(&cnt[seg], 1);
}

__global__ __launch_bounds__(256) void scan1_kernel(
    const int* __restrict__ cnt, int* __restrict__ rp, int* __restrict__ bsum)
{
    __shared__ int sh[256];
    int t = threadIdx.x;
    int base = blockIdx.x * 1024 + t * 4;
    int a0 = (base + 0 < NSEG) ? cnt[base + 0] : 0;
    int a1 = (base + 1 < NSEG) ? cnt[base + 1] : 0;
    int a2 = (base + 2 < NSEG) ? cnt[base + 2] : 0;
    int a3 = (base + 3 < NSEG) ? cnt[base + 3] : 0;
    int s = a0 + a1 + a2 + a3;
    sh[t] = s;
    __syncthreads();
    for (int off = 1; off < 256; off <<= 1) {
        int v = (t >= off) ? sh[t - off] : 0;
        __syncthreads();
        sh[t] += v;
        __syncthreads();
    }
    int excl = sh[t] - s;
    if (t == 255) bsum[blockIdx.x] = sh[255];
    if (base + 0 < NSEG) rp[base + 0] = excl;
    if (base + 1 < NSEG) rp[base + 1] = excl + a0;
    if (base + 2 < NSEG) rp[base + 2] = excl + a0 + a1;
    if (base + 3 < NSEG) rp[base + 3] = excl + a0 + a1 + a2;
}

__global__ __launch_bounds__(256) void scan2_kernel(int* __restrict__ bsum, int nb)
{
    __shared__ int sh[256];
    int t = threadIdx.x;
    int v = (t < nb) ? bsum[t] : 0;
    sh[t] = v;
    __syncthreads();
    for (int off = 1; off < 256; off <<= 1) {
        int u = (t >= off) ? sh[t - off] : 0;
        __syncthreads();
        sh[t] += u;
        __syncthreads();
    }
    if (t < nb) bsum[t] = sh[t] - v;   // exclusive
}

__global__ __launch_bounds__(256) void scan3_kernel(
    int* __restrict__ rp, const int* __restrict__ bsum, int* __restrict__ cursor)
{
    int i = blockIdx.x * 256 + threadIdx.x;
    if (i == 0) rp[NSEG] = NE;
    if (i >= NSEG) return;
    int v = rp[i] + bsum[i >> 10];
    rp[i] = v;
    cursor[i] = v;
}

// store src node id directly into CSR slot (kills one indirection in attn)
__global__ __launch_bounds__(256) void reorder_kernel(
    const int* __restrict__ edge_index, const int* __restrict__ edge_type,
    int* __restrict__ cursor, int* __restrict__ esrc)
{
    int e = blockIdx.x * 256 + threadIdx.x;
    if (e >= NE) return;
    int seg = edge_type[e] * NN + edge_index[NE + e];
    int pos = atomicAdd(&cursor[seg], 1);
    esrc[pos] = edge_index[e];
}

// ======================================================================
// Gather attention: ONE WAVE per segment, all 4 heads at once. Single
// pass, online softmax, 2-way unrolled dual accumulator chains.
// ======================================================================
__global__ __launch_bounds__(256) void attn_kernel(
    const ushort* __restrict__ qkv, const int* __restrict__ esrc,
    const int* __restrict__ rp, ushort* __restrict__ aggb)
{
    int seg  = blockIdx.x * 4 + (threadIdx.x >> 6);   // 4 waves/block, grid exact
    int lane = threadIdx.x & 63;
    int t = seg / NN;
    int d = seg - t * NN;
    ushort* outp = aggb + (size_t)d * (RT * HDIM) + t * HDIM + lane * 4;

    int begin = rp[seg], end = rp[seg + 1];
    if (begin == end) {               // empty segment -> zeros (matches segment_sum)
        ushort4 z; z.x = 0; z.y = 0; z.z = 0; z.w = 0;
        *(ushort4*)outp = z;
        return;
    }

    const size_t sMat = (size_t)RT * NN * HDIM;
    const ushort* Kbase = qkv + sMat     + (size_t)t * NN * HDIM + lane * 4;
    const ushort* Vbase = qkv + 2 * sMat + (size_t)t * NN * HDIM + lane * 4;

    ushort4 q4 = *(const ushort4*)(qkv + ((size_t)t * NN + d) * HDIM + lane * 4);
    float qx = bf2f(q4.x), qy = bf2f(q4.y), qz = bf2f(q4.z), qw = bf2f(q4.w);

    float mx0 = -1e30f, den0 = 0.f, a00 = 0.f, a01 = 0.f, a02 = 0.f, a03 = 0.f;
    float mx1 = -1e30f, den1 = 0.f, a10 = 0.f, a11 = 0.f, a12 = 0.f, a13 = 0.f;

    int p = begin;
    for (; p + 2 <= end; p += 2) {
        int s0 = esrc[p];
        int s1 = esrc[p + 1];
        ushort4 k0 = *(const ushort4*)(Kbase + (size_t)s0 * HDIM);
        ushort4 k1 = *(const ushort4*)(Kbase + (size_t)s1 * HDIM);
        ushort4 v0 = *(const ushort4*)(Vbase + (size_t)s0 * HDIM);
        ushort4 v1 = *(const ushort4*)(Vbase + (size_t)s1 * HDIM);
        float p0 = qx * bf2f(k0.x) + qy * bf2f(k0.y) + qz * bf2f(k0.z) + qw * bf2f(k0.w);
        float p1 = qx * bf2f(k1.x) + qy * bf2f(k1.y) + qz * bf2f(k1.z) + qw * bf2f(k1.w);
        p0 += __shfl_xor(p0, 1); p1 += __shfl_xor(p1, 1);
        p0 += __shfl_xor(p0, 2); p1 += __shfl_xor(p1, 2);
        p0 += __shfl_xor(p0, 4); p1 += __shfl_xor(p1, 4);
        p0 += __shfl_xor(p0, 8); p1 += __shfl_xor(p1, 8);
        p0 *= 0.125f;            p1 *= 0.125f;
        float nm0 = fmaxf(mx0, p0),      nm1 = fmaxf(mx1, p1);
        float c0  = __expf(mx0 - nm0),   c1  = __expf(mx1 - nm1);
        float w0  = __expf(p0 - nm0),    w1  = __expf(p1 - nm1);
        den0 = den0 * c0 + w0;           den1 = den1 * c1 + w1;
        a00 = a00 * c0 + w0 * bf2f(v0.x); a10 = a10 * c1 + w1 * bf2f(v1.x);
        a01 = a01 * c0 + w0 * bf2f(v0.y); a11 = a11 * c1 + w1 * bf2f(v1.y);
        a02 = a02 * c0 + w0 * bf2f(v0.z); a12 = a12 * c1 + w1 * bf2f(v1.z);
        a03 = a03 * c0 + w0 * bf2f(v0.w); a13 = a13 * c1 + w1 * bf2f(v1.w);
        mx0 = nm0;                        mx1 = nm1;
    }
    if (p < end) {   // odd tail -> chain 0
        int s0 = esrc[p];
        ushort4 k0 = *(const ushort4*)(Kbase + (size_t)s0 * HDIM);
        ushort4 v0 = *(const ushort4*)(Vbase + (size_t)s0 * HDIM);
        float p0 = qx * bf2f(k0.x) + qy * bf2f(k0.y) + qz * bf2f(k0.z) + qw * bf2f(k0.w);
        p0 += __shfl_xor(p0, 1); p0 += __shfl_xor(p0, 2);
        p0 += __shfl_xor(p0, 4); p0 += __shfl_xor(p0, 8);
        p0 *= 0.125f;
        float nm0 = fmaxf(mx0, p0);
        float c0  = __expf(mx0 - nm0);
        float w0  = __expf(p0 - nm0);
        den0 = den0 * c0 + w0;
        a00 = a00 * c0 + w0 * bf2f(v0.x);
        a01 = a01 * c0 + w0 * bf2f(v0.y);
        a02 = a02 * c0 + w0 * bf2f(v0.z);
        a03 = a03 * c0 + w0 * bf2f(v0.w);
        mx0 = nm0;
    }
    // merge the two chains (chain1 empty -> c1 = exp(-1e30-m) = 0)
    float m  = fmaxf(mx0, mx1);
    float c0 = __expf(mx0 - m), c1 = __expf(mx1 - m);
    float den = den0 * c0 + den1 * c1;
    float inv = 1.0f / den;
    ushort4 o;
    o.x = f2bf((a00 * c0 + a10 * c1) * inv);
    o.y = f2bf((a01 * c0 + a11 * c1) * inv);
    o.z = f2bf((a02 * c0 + a12 * c1) * inv);
    o.w = f2bf((a03 * c0 + a13 * c1) * inv);
    *(ushort4*)outp = o;
}

// ======================================================================
// bf16 MFMA GEMM (round-7/13 structure — proven best):
// 128x128 tile, BK=32, single-buffer gload_lds staging, swizzled both
// sides; LDS-repack coalesced epilogue. swap2: (y,z) on fast grid axis
// for A-panel L2 reuse. mlp_z >= 0: bias+relu apply ONLY to z == mlp_z
// (lets the routing-MLP GEMM ride as an extra z-plane of the QKV batch).
// ======================================================================
__global__ __launch_bounds__(256) void gemm_bf16_nt(
    const ushort* __restrict__ A, const ushort* __restrict__ B,
    const float* __restrict__ bias, const float* __restrict__ gatep,
    ushort* __restrict__ Cout,
    int M, int Kd, int lda, int ldb, int ldc,
    long long sA, long long sB, long long sBias, long long sC,
    int relu, int gate_mode, int swap2, int mlp_z)
{
    int bxi, byi, z;
    if (swap2) {   // grid (ny*nz, gx): blockIdx.x = y + 2*z (ny==2), blockIdx.y = row tile
        bxi = blockIdx.y;
        byi = blockIdx.x & 1;
        z   = blockIdx.x >> 1;
    } else {
        bxi = blockIdx.x;
        byi = blockIdx.y;
        z   = blockIdx.z;
    }
    A += (size_t)z * sA;
    B += (size_t)z * sB;
    const float* biasp = bias;
    int do_relu = relu;
    if (mlp_z >= 0) {
        if (z == mlp_z) do_relu = 1;
        else            biasp = nullptr;
    } else if (biasp) {
        biasp += (size_t)z * sBias;
    }

    __shared__ ushort smem[128 * 128];   // 32 KB: As(8K)+Bs(8K) in loop; C-tile after
    ushort* As = smem;
    ushort* Bs = smem + 4096;

    const int tid  = threadIdx.x;
    const int lane = tid & 63;
    const int wid  = tid >> 6;
    const int wr   = (wid >> 1) * 64;
    const int wc   = (wid & 1) * 64;
    const int bm   = bxi * 128;
    const int bn   = byi * 128;

    f32x4 acc[4][4];
    #pragma unroll
    for (int m = 0; m < 4; ++m)
        #pragma unroll
        for (int n = 0; n < 4; ++n)
            #pragma unroll
            for (int e = 0; e < 4; ++e) acc[m][n][e] = 0.f;

    const int r0    = lane & 15;
    const int slotq = lane >> 4;          // logical 16B k-slot (0..3)

    const int srow0 = ((wid << 1) << 4) + (lane >> 2);       // chunk c=0 row
    const int scol0 = (((lane & 3) ^ ((srow0 >> 1) & 3)) << 3);
    const int srow1 = srow0 + 16;                            // chunk c=1 row
    const int scol1 = (((lane & 3) ^ ((srow1 >> 1) & 3)) << 3);
    const int ga0 = bm + srow0 < M ? bm + srow0 : M - 1;
    const int ga1 = bm + srow1 < M ? bm + srow1 : M - 1;

    for (int k0 = 0; k0 < Kd; k0 += 32) {
        gload_lds16(A + (size_t)ga0 * lda + k0 + scol0, &As[(wid << 1) * 512]);
        gload_lds16(A + (size_t)ga1 * lda + k0 + scol1, &As[((wid << 1) + 1) * 512]);
        gload_lds16(B + (size_t)(bn + srow0) * ldb + k0 + scol0, &Bs[(wid << 1) * 512]);
        gload_lds16(B + (size_t)(bn + srow1) * ldb + k0 + scol1, &Bs[((wid << 1) + 1) * 512]);
        __syncthreads();
        short8 a[4], b[4];
        #pragma unroll
        for (int m = 0; m < 4; ++m) {
            int rr = wr + m * 16 + r0;
            a[m] = *(const short8*)(&As[rr * 32 + ((slotq ^ ((rr >> 1) & 3)) << 3)]);
        }
        #pragma unroll
        for (int n = 0; n < 4; ++n) {
            int rr = wc + n * 16 + r0;
            b[n] = *(const short8*)(&Bs[rr * 32 + ((slotq ^ ((rr >> 1) & 3)) << 3)]);
        }
        #pragma unroll
        for (int m = 0; m < 4; ++m)
            #pragma unroll
            for (int n = 0; n < 4; ++n)
                acc[m][n] = __builtin_amdgcn_mfma_f32_16x16x32_bf16(a[m], b[n], acc[m][n], 0, 0, 0);
        __syncthreads();
    }

    const int cr = (lane >> 4) * 4;
    const int cc = lane & 15;
    #pragma unroll
    for (int m = 0; m < 4; ++m) {
        #pragma unroll
        for (int j = 0; j < 4; ++j) {
            int row  = wr + m * 16 + cr + j;
            int grow = bm + row;
            float g = 1.0f;
            if (gate_mode) g = (grow < M) ? gatep[(size_t)grow * KS + z] : 0.f;
            int sw = ((row >> 2) & 3) << 5;
            #pragma unroll
            for (int n = 0; n < 4; ++n) {
                int col = wc + n * 16 + cc;
                float v = acc[m][n][j];
                if (biasp) v += biasp[bn + col];
                if (do_relu) v = fmaxf(v, 0.f);
                v *= g;
                *(ushort*)((char*)smem + row * 256 + ((col * 2) ^ sw)) = f2bf(v);
            }
        }
    }
    __syncthreads();
    #pragma unroll
    for (int it = 0; it < 8; ++it) {
        int row  = it * 16 + (tid >> 4);
        int grow = bm + row;
        int sw   = ((row >> 2) & 3) << 5;
        ushort8 vv = *(const ushort8*)((const char*)smem + row * 256 + (((tid & 15) * 16) ^ sw));
        if (grow < M)
            *(ushort8*)(Cout + (size_t)z * sC + (size_t)grow * ldc + bn + (tid & 15) * 8) = vv;
    }
}

// ======================================================================
// Fused symw-mix + symptom GEMM. A_virt[n][i] = sum_r symw[z][r]*
// aggb[n][r*256+i]. Grid (16, 157): (y,z) on FAST axis so 16 consecutive
// blocks share one 256KB aggb row-panel. A reg-staged + swizzled
// ds_write; B via gload_lds. K-loop sync == gemm_bf16_nt.
// ======================================================================
__global__ __launch_bounds__(256) void gemm_amix(
    const ushort* __restrict__ aggb, const ushort* __restrict__ Wsym,
    const float* __restrict__ b_sym, const float* __restrict__ gatep,
    const float* __restrict__ symw, ushort* __restrict__ catb, int M)
{
    const int y  = blockIdx.x & 1;
    const int z  = blockIdx.x >> 1;
    const int bm = blockIdx.y * 128;
    const int bn = y * 128;
    const ushort* B = Wsym + (size_t)z * HDIM * HDIM;
    const float sw0 = symw[z * RT + 0], sw1 = symw[z * RT + 1];
    const float sw2 = symw[z * RT + 2], sw3 = symw[z * RT + 3];

    __shared__ ushort smem[128 * 128];
    ushort* As = smem;
    ushort* Bs = smem + 4096;

    const int tid  = threadIdx.x;
    const int lane = tid & 63;
    const int wid  = tid >> 6;
    const int wr   = (wid >> 1) * 64;
    const int wc   = (wid & 1) * 64;

    f32x4 acc[4][4];
    #pragma unroll
    for (int m = 0; m < 4; ++m)
        #pragma unroll
        for (int n = 0; n < 4; ++n)
            #pragma unroll
            for (int e = 0; e < 4; ++e) acc[m][n][e] = 0.f;

    const int r0    = lane & 15;
    const int slotq = lane >> 4;

    const int srow0 = ((wid << 1) << 4) + (lane >> 2);
    const int scol0 = (((lane & 3) ^ ((srow0 >> 1) & 3)) << 3);
    const int srow1 = srow0 + 16;
    const int scol1 = (((lane & 3) ^ ((srow1 >> 1) & 3)) << 3);

    const int arow0 = tid >> 2,          asl = tid & 3;
    const int arow1 = arow0 + 64;
    const int gaa0 = (bm + arow0 < M) ? bm + arow0 : M - 1;
    const int gaa1 = (bm + arow1 < M) ? bm + arow1 : M - 1;
    const int aoff0 = arow0 * 32 + ((asl ^ ((arow0 >> 1) & 3)) << 3);
    const int aoff1 = arow1 * 32 + ((asl ^ ((arow1 >> 1) & 3)) << 3);

    for (int k0 = 0; k0 < HDIM; k0 += 32) {
        gload_lds16(B + (size_t)(bn + srow0) * HDIM + k0 + scol0, &Bs[(wid << 1) * 512]);
        gload_lds16(B + (size_t)(bn + srow1) * HDIM + k0 + scol1, &Bs[((wid << 1) + 1) * 512]);
        {
            const ushort* ab0 = aggb + (size_t)gaa0 * (RT * HDIM) + k0 + asl * 8;
            const ushort* ab1 = aggb + (size_t)gaa1 * (RT * HDIM) + k0 + asl * 8;
            ushort8 u00 = *(const ushort8*)(ab0);
            ushort8 u01 = *(const ushort8*)(ab0 + HDIM);
            ushort8 u02 = *(const ushort8*)(ab0 + 2 * HDIM);
            ushort8 u03 = *(const ushort8*)(ab0 + 3 * HDIM);
            ushort8 u10 = *(const ushort8*)(ab1);
            ushort8 u11 = *(const ushort8*)(ab1 + HDIM);
            ushort8 u12 = *(const ushort8*)(ab1 + 2 * HDIM);
            ushort8 u13 = *(const ushort8*)(ab1 + 3 * HDIM);
            ushort8 o0, o1;
            #pragma unroll
            for (int j = 0; j < 8; ++j) {
                o0[j] = f2bf(sw0 * bf2f((ushort)u00[j]) + sw1 * bf2f((ushort)u01[j]) +
                             sw2 * bf2f((ushort)u02[j]) + sw3 * bf2f((ushort)u03[j]));
                o1[j] = f2bf(sw0 * bf2f((ushort)u10[j]) + sw1 * bf2f((ushort)u11[j]) +
                             sw2 * bf2f((ushort)u12[j]) + sw3 * bf2f((ushort)u13[j]));
            }
            *(ushort8*)(&As[aoff0]) = o0;
            *(ushort8*)(&As[aoff1]) = o1;
        }
        __syncthreads();
        short8 a[4], b[4];
        #pragma unroll
        for (int m = 0; m < 4; ++m) {
            int rr = wr + m * 16 + r0;
            a[m] = *(const short8*)(&As[rr * 32 + ((slotq ^ ((rr >> 1) & 3)) << 3)]);
        }
        #pragma unroll
        for (int n = 0; n < 4; ++n) {
            int rr = wc + n * 16 + r0;
            b[n] = *(const short8*)(&Bs[rr * 32 + ((slotq ^ ((rr >> 1) & 3)) << 3)]);
        }
        #pragma unroll
        for (int m = 0; m < 4; ++m)
            #pragma unroll
            for (int n = 0; n < 4; ++n)
                acc[m][n] = __builtin_amdgcn_mfma_f32_16x16x32_bf16(a[m], b[n], acc[m][n], 0, 0, 0);
        __syncthreads();
    }

    const int cr = (lane >> 4) * 4;
    const int cc = lane & 15;
    #pragma unroll
    for (int m = 0; m < 4; ++m) {
        #pragma unroll
        for (int j = 0; j < 4; ++j) {
            int row  = wr + m * 16 + cr + j;
            int grow = bm + row;
            float g = (grow < M) ? gatep[(size_t)grow * KS + z] : 0.f;
            int sw = ((row >> 2) & 3) << 5;
            #pragma unroll
            for (int n = 0; n < 4; ++n) {
                int col = wc + n * 16 + cc;
                float v = acc[m][n][j] + b_sym[z * HDIM + bn + col];
                v = fmaxf(v, 0.f) * g;
                *(ushort*)((char*)smem + row * 256 + ((col * 2) ^ sw)) = f2bf(v);
            }
        }
    }
    __syncthreads();
    #pragma unroll
    for (int it = 0; it < 8; ++it) {
        int row  = it * 16 + (tid >> 4);
        int grow = bm + row;
        int sw   = ((row >> 2) & 3) << 5;
        ushort8 vv = *(const ushort8*)((const char*)smem + row * 256 + (((tid & 15) * 16) ^ sw));
        if (grow < M)
            *(ushort8*)(catb + (size_t)grow * (KS * HDIM) + z * HDIM + bn + (tid & 15) * 8) = vv;
    }
}

// gate: logits = hid @ w2.T + b2 ; softmax over K. One wave per node. hid bf16.
__global__ __launch_bounds__(256) void gate_kernel(
    const ushort* __restrict__ hid, const float* __restrict__ w2,
    const float* __restrict__ b2, float* __restrict__ gate)
{
    int wid = threadIdx.x >> 6, lane = threadIdx.x & 63;
    int n = blockIdx.x * 4 + wid;
    if (n >= NN) return;
    ushort4 h4 = *(const ushort4*)(hid + (size_t)n * HDIM + lane * 4);
    float hx = bf2f(h4.x), hy = bf2f(h4.y), hz = bf2f(h4.z), hw = bf2f(h4.w);
    float lg[KS];
    #pragma unroll
    for (int k = 0; k < KS; ++k) {
        const float4 wv = *(const float4*)(w2 + k * HDIM + lane * 4);
        float p = hx * wv.x + hy * wv.y + hz * wv.z + hw * wv.w;
        #pragma unroll
        for (int m = 1; m < 64; m <<= 1) p += __shfl_xor(p, m);
        lg[k] = p + b2[k];
    }
    float m = lg[0];
    #pragma unroll
    for (int k = 1; k < KS; ++k) m = fmaxf(m, lg[k]);
    float ssum = 0.f;
    #pragma unroll
    for (int k = 0; k < KS; ++k) ssum += __expf(lg[k] - m);
    float inv = 1.0f / ssum;
    #pragma unroll
    for (int k = 0; k < KS; ++k)
        if (lane == k) gate[(size_t)n * KS + k] = __expf(lg[k] - m) * inv;
}

// residual + layernorm. One wave per node. hnew bf16.
__global__ __launch_bounds__(256) void ln_kernel(
    const float* __restrict__ h, const ushort* __restrict__ hnew,
    const float* __restrict__ gamma, const float* __restrict__ beta,
    float* __restrict__ out)
{
    int wid = threadIdx.x >> 6, lane = threadIdx.x & 63;
    int n = blockIdx.x * 4 + wid;
    if (n >= NN) return;
    size_t off = (size_t)n * HDIM + lane * 4;
    const float4 a = *(const float4*)(h + off);
    ushort4 b4 = *(const ushort4*)(hnew + off);
    float4 x = make_float4(a.x + bf2f(b4.x), a.y + bf2f(b4.y),
                           a.z + bf2f(b4.z), a.w + bf2f(b4.w));
    float s1 = x.x + x.y + x.z + x.w;
    float s2 = x.x * x.x + x.y * x.y + x.z * x.z + x.w * x.w;
    #pragma unroll
    for (int m = 1; m < 64; m <<= 1) { s1 += __shfl_xor(s1, m); s2 += __shfl_xor(s2, m); }
    float mu = s1 * (1.0f / HDIM);
    float var = s2 * (1.0f / HDIM) - mu * mu;
    float inv = rsqrtf(var + LN_EPS);
    const float4 g  = *(const float4*)(gamma + lane * 4);
    const float4 be = *(const float4*)(beta + lane * 4);
    float4 o;
    o.x = (x.x - mu) * inv * g.x + be.x;
    o.y = (x.y - mu) * inv * g.y + be.y;
    o.z = (x.z - mu) * inv * g.z + be.z;
    o.w = (x.w - mu) * inv * g.w + be.w;
    *(float4*)(out + off) = o;
}

extern "C" void kernel_launch(void* const* d_in, const int* in_sizes, int n_in,
                              void* d_out, int out_size, void* d_ws, size_t ws_size,
                              hipStream_t stream) {
    const float* h          = (const float*)d_in[0];
    const int*   edge_index = (const int*)d_in[1];
    const int*   edge_type  = (const int*)d_in[2];
    const float* W_q        = (const float*)d_in[3];
    const float* W_k        = (const float*)d_in[4];
    const float* W_v        = (const float*)d_in[5];
    const float* mlp_w1     = (const float*)d_in[6];
    const float* mlp_b1     = (const float*)d_in[7];
    const float* mlp_w2     = (const float*)d_in[8];
    const float* mlp_b2     = (const float*)d_in[9];
    const float* sym_logits = (const float*)d_in[10];
    const float* W_sym      = (const float*)d_in[11];
    const float* b_sym      = (const float*)d_in[12];
    const float* W_cross    = (const float*)d_in[13];
    const float* b_cross    = (const float*)d_in[14];
    const float* ln_gamma   = (const float*)d_in[15];
    const float* ln_beta    = (const float*)d_in[16];
    float* out = (float*)d_out;
    char*  ws  = (char*)d_ws;

    ushort* qkv    = (ushort*)(ws + OFFB_QKV);
    ushort* hnew   = (ushort*)(ws + OFFB_HNEW);
    ushort* catb   = (ushort*)(ws + OFFB_CATB);
    ushort* hid    = (ushort*)(ws + OFFB_HID);   // == qkv + 12*sNH (contiguous plane 12)
    ushort* aggb   = (ushort*)(ws + OFFB_AGGB);
    ushort* hb     = (ushort*)(ws + OFFB_HB);
    float*  gate   = (float*)(ws + OFFB_GATE);
    ushort* wqkvb  = (ushort*)(ws + OFFB_WQKV);
    ushort* w1b    = (ushort*)(ws + OFFB_W1);    // == wqkvb + 12*H*H (contiguous)
    ushort* wsymb  = (ushort*)(ws + OFFB_WSYM);
    ushort* wxb    = (ushort*)(ws + OFFB_WX);
    float*  symw   = (float*)(ws + OFFB_SYMW);
    int*    cnt    = (int*)(ws + OFFB_CNT);
    int*    rp     = (int*)(ws + OFFB_RP);
    int*    bsum   = (int*)(ws + OFFB_BSUM);
    int*    cursor = (int*)(ws + OFFB_CUR);
    int*    esrc   = (int*)(ws + OFFB_ESRC);

    const long long sRHH = (long long)RT * HDIM * HDIM;   // per-mat weight stride
    const long long sNH  = (long long)NN * HDIM;          // per-z output stride

    // ---- conversions ----
    cvt_bf16_kernel<<<5000, 256, 0, stream>>>(h, hb, NN * HDIM / 4);
    cvt_bf16_kernel<<<256, 256, 0, stream>>>(W_q, wqkvb,            RT * HDIM * HDIM / 4);
    cvt_bf16_kernel<<<256, 256, 0, stream>>>(W_k, wqkvb + sRHH,     RT * HDIM * HDIM / 4);
    cvt_bf16_kernel<<<256, 256, 0, stream>>>(W_v, wqkvb + 2 * sRHH, RT * HDIM * HDIM / 4);
    cvt_bf16_kernel<<<64, 256, 0, stream>>>(mlp_w1, w1b, HDIM * HDIM / 4);
    cvt_bf16_kernel<<<512, 256, 0, stream>>>(W_sym, wsymb, KS * HDIM * HDIM / 4);
    cvt_bf16_kernel<<<512, 256, 0, stream>>>(W_cross, wxb, HDIM * KS * HDIM / 4);
    symw_kernel<<<1, 64, 0, stream>>>(sym_logits, symw);

    // ---- QKV + routing-MLP in ONE batched GEMM: z = mat*4+t for z<12,
    //      z==12 is hid = relu(hb @ w1b.T + mlp_b1) (weights & outputs
    //      are laid out contiguously). (y,z) on fast axis for A-panel reuse.
    gemm_bf16_nt<<<dim3(26, 157, 1), 256, 0, stream>>>(hb, wqkvb, mlp_b1, nullptr, qkv,
        NN, HDIM, HDIM, HDIM, HDIM, 0, (long long)HDIM * HDIM, 0, sNH, 0, 0, 1, 12);

    gate_kernel<<<NN / 4, 256, 0, stream>>>(hid, mlp_w2, mlp_b2, gate);

    // ---- CSR build over seg = t*N + dst ----
    hipMemsetAsync(cnt, 0, NSEG * sizeof(int), stream);
    hist_kernel<<<NE / 256, 256, 0, stream>>>(edge_index, edge_type, cnt);
    scan1_kernel<<<79, 256, 0, stream>>>(cnt, rp, bsum);
    scan2_kernel<<<1, 256, 0, stream>>>(bsum, 79);
    scan3_kernel<<<313, 256, 0, stream>>>(rp, bsum, cursor);
    reorder_kernel<<<NE / 256, 256, 0, stream>>>(edge_index, edge_type, cursor, esrc);

    // ---- gather attention: one wave per segment, single pass, dual chains ----
    attn_kernel<<<NSEG / 4, 256, 0, stream>>>(qkv, esrc, rp, aggb);

    // ---- FUSED symw-mix + symptom GEMM -> catb (N, K*H) ----
    gemm_amix<<<dim3(16, 157), 256, 0, stream>>>(aggb, wsymb, b_sym, gate, symw, catb, NN);

    // ---- cross GEMM: hnew = relu(catb @ W_cross.T + b_cross); swap2 so the
    //      2 blocks sharing each catb row-panel are dispatched adjacently ----
    gemm_bf16_nt<<<dim3(2, 157, 1), 256, 0, stream>>>(catb, wxb, b_cross, nullptr, hnew,
        NN, KS * HDIM, KS * HDIM, KS * HDIM, HDIM, 0, 0, 0, 0, 1, 0, 1, -1);

    // ---- residual + layernorm ----
    ln_kernel<<<NN / 4, 256, 0, stream>>>(h, hnew, ln_gamma, ln_beta, out);
}

// Round 18
// 354.134 us; speedup vs baseline: 1.2647x; 1.0236x over previous
//
#include <hip/hip_runtime.h>

// ---- problem constants ----
#define NN     20000   // nodes
#define HDIM   256     // hidden
#define RT     4       // relation types
#define KS     8       // symptom channels
#define NHEAD  4
#define HDHEAD 64
#define NE     320000  // edges
#define NSEG   (RT * NN)   // 80000 segments
#define LN_EPS 1e-5f
// SCALE = sqrt(64) = 8

typedef __attribute__((ext_vector_type(8))) short short8;            // 8 bf16 = 4 VGPRs
typedef __attribute__((ext_vector_type(8))) unsigned short ushort8;  // 8 bf16
typedef __attribute__((ext_vector_type(4))) float f32x4;

// ---- workspace layout (BYTE offsets) ----
// RACE FIX (r16/r17 failure): catb previously overlapped aggb; amix's writes
// clobbered aggb panels still being read once block order changed. New layout:
//   qkv+hid [0, 133.12M) -> after attn, planes 0-7 are dead:
//   catb    [0, 81.92M)   (over dead qkv planes 0-7)
//   hnew    [81.92M, 92.16M) (over dead qkv plane 8)
//   aggb    [133.12M, 174.08M)  -- DISJOINT from catb & hnew under ANY order.
static constexpr size_t OFFB_QKV  = 0;
static constexpr size_t OFFB_CATB = 0;           // bf16 (N,K*H) 81.92M, over dead qkv planes 0-7
static constexpr size_t OFFB_HNEW = 81920000;    // bf16 (N,H) 10.24M, over dead qkv plane 8
static constexpr size_t OFFB_HID  = 122880000;   // bf16 (N,H) = qkv plane 12 (contiguous!)
static constexpr size_t OFFB_AGGB = 133120000;   // bf16 (N,R*H) 40.96M, ends 174,080,000
static constexpr size_t OFFB_HB   = 174080000;   // bf16 h (N,H) 10.24M
static constexpr size_t OFFB_GATE = 184320000;   // fp32 (N,KS) 640K
static constexpr size_t OFFB_WQKV = 184960000;   // bf16 [3][RT][H][H] 1,572,864
static constexpr size_t OFFB_W1   = 186532864;   // bf16 (H,H) 131,072  (contiguous after WQKV)
static constexpr size_t OFFB_WSYM = 186663936;   // bf16 (K,H,H) 1,048,576
static constexpr size_t OFFB_WX   = 187712512;   // bf16 (H,K*H) 1,048,576
static constexpr size_t OFFB_SYMW = 188761088;   // fp32 (K,R) pad 256
static constexpr size_t OFFB_CNT  = 188761344;   // int [NSEG] 320,000
static constexpr size_t OFFB_RP   = 189081344;   // int [NSEG+1] pad 320,016
static constexpr size_t OFFB_BSUM = 189401360;   // int [128] 512
static constexpr size_t OFFB_CUR  = 189401872;   // int [NSEG] 320,000
static constexpr size_t OFFB_ESRC = 189721872;   // int [NE] 1,280,000
// end = 191,001,872 B (~182.2 MiB) -- known-good ws >= 197.7 MB

// ---- helpers ----
__device__ inline ushort f2bf(float f) {
    unsigned u = __float_as_uint(f);
    unsigned r = (u + 0x7FFFu + ((u >> 16) & 1u)) >> 16;
    return (ushort)r;
}
__device__ inline float bf2f(ushort u) { return __uint_as_float(((unsigned)u) << 16); }

// direct global->LDS DMA, 16B per lane. lds dest = wave-uniform base + lane*16.
__device__ inline void gload_lds16(const ushort* g, ushort* l) {
    __builtin_amdgcn_global_load_lds(
        (const __attribute__((address_space(1))) void*)g,
        (__attribute__((address_space(3))) void*)l, 16, 0, 0);
}

// ======================================================================
// f32 -> bf16 convert (4 elems/thread)
// ======================================================================
__global__ __launch_bounds__(256) void cvt_bf16_kernel(
    const float* __restrict__ in, ushort* __restrict__ out, int n4)
{
    int g = blockIdx.x * 256 + threadIdx.x;
    if (g >= n4) return;
    float4 v = *(const float4*)(in + (size_t)g * 4);
    ushort4 o;
    o.x = f2bf(v.x); o.y = f2bf(v.y); o.z = f2bf(v.z); o.w = f2bf(v.w);
    *(ushort4*)(out + (size_t)g * 4) = o;
}

// softmax over R of sym_edge_logits rows -> symw (K x R)
__global__ void symw_kernel(const float* __restrict__ logits, float* __restrict__ symw)
{
    int k = threadIdx.x;
    if (k >= KS) return;
    float v[RT]; float m = -1e30f;
    #pragma unroll
    for (int r = 0; r < RT; ++r) { v[r] = logits[k * RT + r]; m = fmaxf(m, v[r]); }
    float ssum = 0.f;
    #pragma unroll
    for (int r = 0; r < RT; ++r) { v[r] = __expf(v[r] - m); ssum += v[r]; }
    #pragma unroll
    for (int r = 0; r < RT; ++r) symw[k * RT + r] = v[r] / ssum;
}

// ======================================================================
// CSR build: histogram -> 2-level exclusive scan -> reorder
// ======================================================================
__global__ __launch_bounds__(256) void hist_kernel(
    const int* __restrict__ edge_index, const int* __restrict__ edge_type,
    int* __restrict__ cnt)
{
    int e = blockIdx.x * 256 + threadIdx.x;
    if (e >= NE) return;
    int seg = edge_type[e] * NN + edge_index[NE + e];
    atomicAdd(&cnt[seg], 1);
}

__global__ __launch_bounds__(256) void scan1_kernel(
    const int* __restrict__ cnt, int* __restrict__ rp, int* __restrict__ bsum)
{
    __shared__ int sh[256];
    int t = threadIdx.x;
    int base = blockIdx.x * 1024 + t * 4;
    int a0 = (base + 0 < NSEG) ? cnt[base + 0] : 0;
    int a1 = (base + 1 < NSEG) ? cnt[base + 1] : 0;
    int a2 = (base + 2 < NSEG) ? cnt[base + 2] : 0;
    int a3 = (base + 3 < NSEG) ? cnt[base + 3] : 0;
    int s = a0 + a1 + a2 + a3;
    sh[t] = s;
    __syncthreads();
    for (int off = 1; off < 256; off <<= 1) {
        int v = (t >= off) ? sh[t - off] : 0;
        __syncthreads();
        sh[t] += v;
        __syncthreads();
    }
    int excl = sh[t] - s;
    if (t == 255) bsum[blockIdx.x] = sh[255];
    if (base + 0 < NSEG) rp[base + 0] = excl;
    if (base + 1 < NSEG) rp[base + 1] = excl + a0;
    if (base + 2 < NSEG) rp[base + 2] = excl + a0 + a1;
    if (base + 3 < NSEG) rp[base + 3] = excl + a0 + a1 + a2;
}

__global__ __launch_bounds__(256) void scan2_kernel(int* __restrict__ bsum, int nb)
{
    __shared__ int sh[256];
    int t = threadIdx.x;
    int v = (t < nb) ? bsum[t] : 0;
    sh[t] = v;
    __syncthreads();
    for (int off = 1; off < 256; off <<= 1) {
        int u = (t >= off) ? sh[t - off] : 0;
        __syncthreads();
        sh[t] += u;
        __syncthreads();
    }
    if (t < nb) bsum[t] = sh[t] - v;   // exclusive
}

__global__ __launch_bounds__(256) void scan3_kernel(
    int* __restrict__ rp, const int* __restrict__ bsum, int* __restrict__ cursor)
{
    int i = blockIdx.x * 256 + threadIdx.x;
    if (i == 0) rp[NSEG] = NE;
    if (i >= NSEG) return;
    int v = rp[i] + bsum[i >> 10];
    rp[i] = v;
    cursor[i] = v;
}

// store src node id directly into CSR slot (kills one indirection in attn)
__global__ __launch_bounds__(256) void reorder_kernel(
    const int* __restrict__ edge_index, const int* __restrict__ edge_type,
    int* __restrict__ cursor, int* __restrict__ esrc)
{
    int e = blockIdx.x * 256 + threadIdx.x;
    if (e >= NE) return;
    int seg = edge_type[e] * NN + edge_index[NE + e];
    int pos = atomicAdd(&cursor[seg], 1);
    esrc[pos] = edge_index[e];
}

// ======================================================================
// Gather attention: ONE WAVE per segment, all 4 heads at once. Single
// pass, online softmax, 2-way unrolled DUAL accumulator chains (proven).
// ======================================================================
__global__ __launch_bounds__(256) void attn_kernel(
    const ushort* __restrict__ qkv, const int* __restrict__ esrc,
    const int* __restrict__ rp, ushort* __restrict__ aggb)
{
    int seg  = blockIdx.x * 4 + (threadIdx.x >> 6);   // 4 waves/block, grid exact
    int lane = threadIdx.x & 63;
    int t = seg / NN;
    int d = seg - t * NN;
    ushort* outp = aggb + (size_t)d * (RT * HDIM) + t * HDIM + lane * 4;

    int begin = rp[seg], end = rp[seg + 1];
    if (begin == end) {               // empty segment -> zeros (matches segment_sum)
        ushort4 z; z.x = 0; z.y = 0; z.z = 0; z.w = 0;
        *(ushort4*)outp = z;
        return;
    }

    const size_t sMat = (size_t)RT * NN * HDIM;
    const ushort* Kbase = qkv + sMat     + (size_t)t * NN * HDIM + lane * 4;
    const ushort* Vbase = qkv + 2 * sMat + (size_t)t * NN * HDIM + lane * 4;

    ushort4 q4 = *(const ushort4*)(qkv + ((size_t)t * NN + d) * HDIM + lane * 4);
    float qx = bf2f(q4.x), qy = bf2f(q4.y), qz = bf2f(q4.z), qw = bf2f(q4.w);

    float mx0 = -1e30f, den0 = 0.f, a00 = 0.f, a01 = 0.f, a02 = 0.f, a03 = 0.f;
    float mx1 = -1e30f, den1 = 0.f, a10 = 0.f, a11 = 0.f, a12 = 0.f, a13 = 0.f;

    int p = begin;
    for (; p + 2 <= end; p += 2) {
        int s0 = esrc[p];
        int s1 = esrc[p + 1];
        ushort4 k0 = *(const ushort4*)(Kbase + (size_t)s0 * HDIM);
        ushort4 k1 = *(const ushort4*)(Kbase + (size_t)s1 * HDIM);
        ushort4 v0 = *(const ushort4*)(Vbase + (size_t)s0 * HDIM);
        ushort4 v1 = *(const ushort4*)(Vbase + (size_t)s1 * HDIM);
        float p0 = qx * bf2f(k0.x) + qy * bf2f(k0.y) + qz * bf2f(k0.z) + qw * bf2f(k0.w);
        float p1 = qx * bf2f(k1.x) + qy * bf2f(k1.y) + qz * bf2f(k1.z) + qw * bf2f(k1.w);
        p0 += __shfl_xor(p0, 1); p1 += __shfl_xor(p1, 1);
        p0 += __shfl_xor(p0, 2); p1 += __shfl_xor(p1, 2);
        p0 += __shfl_xor(p0, 4); p1 += __shfl_xor(p1, 4);
        p0 += __shfl_xor(p0, 8); p1 += __shfl_xor(p1, 8);
        p0 *= 0.125f;            p1 *= 0.125f;
        float nm0 = fmaxf(mx0, p0),      nm1 = fmaxf(mx1, p1);
        float c0  = __expf(mx0 - nm0),   c1  = __expf(mx1 - nm1);
        float w0  = __expf(p0 - nm0),    w1  = __expf(p1 - nm1);
        den0 = den0 * c0 + w0;           den1 = den1 * c1 + w1;
        a00 = a00 * c0 + w0 * bf2f(v0.x); a10 = a10 * c1 + w1 * bf2f(v1.x);
        a01 = a01 * c0 + w0 * bf2f(v0.y); a11 = a11 * c1 + w1 * bf2f(v1.y);
        a02 = a02 * c0 + w0 * bf2f(v0.z); a12 = a12 * c1 + w1 * bf2f(v1.z);
        a03 = a03 * c0 + w0 * bf2f(v0.w); a13 = a13 * c1 + w1 * bf2f(v1.w);
        mx0 = nm0;                        mx1 = nm1;
    }
    if (p < end) {   // odd tail -> chain 0
        int s0 = esrc[p];
        ushort4 k0 = *(const ushort4*)(Kbase + (size_t)s0 * HDIM);
        ushort4 v0 = *(const ushort4*)(Vbase + (size_t)s0 * HDIM);
        float p0 = qx * bf2f(k0.x) + qy * bf2f(k0.y) + qz * bf2f(k0.z) + qw * bf2f(k0.w);
        p0 += __shfl_xor(p0, 1); p0 += __shfl_xor(p0, 2);
        p0 += __shfl_xor(p0, 4); p0 += __shfl_xor(p0, 8);
        p0 *= 0.125f;
        float nm0 = fmaxf(mx0, p0);
        float c0  = __expf(mx0 - nm0);
        float w0  = __expf(p0 - nm0);
        den0 = den0 * c0 + w0;
        a00 = a00 * c0 + w0 * bf2f(v0.x);
        a01 = a01 * c0 + w0 * bf2f(v0.y);
        a02 = a02 * c0 + w0 * bf2f(v0.z);
        a03 = a03 * c0 + w0 * bf2f(v0.w);
        mx0 = nm0;
    }
    // merge the two chains (chain1 empty -> c1 = exp(-1e30-m) = 0)
    float m  = fmaxf(mx0, mx1);
    float c0 = __expf(mx0 - m), c1 = __expf(mx1 - m);
    float den = den0 * c0 + den1 * c1;
    float inv = 1.0f / den;
    ushort4 o;
    o.x = f2bf((a00 * c0 + a10 * c1) * inv);
    o.y = f2bf((a01 * c0 + a11 * c1) * inv);
    o.z = f2bf((a02 * c0 + a12 * c1) * inv);
    o.w = f2bf((a03 * c0 + a13 * c1) * inv);
    *(ushort4*)outp = o;
}

// ======================================================================
// bf16 MFMA GEMM (round-7/13 structure — proven best):
// 128x128 tile, BK=32, single-buffer gload_lds staging, swizzled both
// sides; LDS-repack coalesced epilogue. swap2: (y,z) on fast grid axis
// for A-panel L2 reuse. mlp_z >= 0: bias+relu apply ONLY to z == mlp_z.
// ======================================================================
__global__ __launch_bounds__(256) void gemm_bf16_nt(
    const ushort* __restrict__ A, const ushort* __restrict__ B,
    const float* __restrict__ bias, const float* __restrict__ gatep,
    ushort* __restrict__ Cout,
    int M, int Kd, int lda, int ldb, int ldc,
    long long sA, long long sB, long long sBias, long long sC,
    int relu, int gate_mode, int swap2, int mlp_z)
{
    int bxi, byi, z;
    if (swap2) {   // grid (ny*nz, gx): blockIdx.x = y + 2*z (ny==2), blockIdx.y = row tile
        bxi = blockIdx.y;
        byi = blockIdx.x & 1;
        z   = blockIdx.x >> 1;
    } else {
        bxi = blockIdx.x;
        byi = blockIdx.y;
        z   = blockIdx.z;
    }
    A += (size_t)z * sA;
    B += (size_t)z * sB;
    const float* biasp = bias;
    int do_relu = relu;
    if (mlp_z >= 0) {
        if (z == mlp_z) do_relu = 1;
        else            biasp = nullptr;
    } else if (biasp) {
        biasp += (size_t)z * sBias;
    }

    __shared__ ushort smem[128 * 128];   // 32 KB: As(8K)+Bs(8K) in loop; C-tile after
    ushort* As = smem;
    ushort* Bs = smem + 4096;

    const int tid  = threadIdx.x;
    const int lane = tid & 63;
    const int wid  = tid >> 6;
    const int wr   = (wid >> 1) * 64;
    const int wc   = (wid & 1) * 64;
    const int bm   = bxi * 128;
    const int bn   = byi * 128;

    f32x4 acc[4][4];
    #pragma unroll
    for (int m = 0; m < 4; ++m)
        #pragma unroll
        for (int n = 0; n < 4; ++n)
            #pragma unroll
            for (int e = 0; e < 4; ++e) acc[m][n][e] = 0.f;

    const int r0    = lane & 15;
    const int slotq = lane >> 4;          // logical 16B k-slot (0..3)

    const int srow0 = ((wid << 1) << 4) + (lane >> 2);       // chunk c=0 row
    const int scol0 = (((lane & 3) ^ ((srow0 >> 1) & 3)) << 3);
    const int srow1 = srow0 + 16;                            // chunk c=1 row
    const int scol1 = (((lane & 3) ^ ((srow1 >> 1) & 3)) << 3);
    const int ga0 = bm + srow0 < M ? bm + srow0 : M - 1;
    const int ga1 = bm + srow1 < M ? bm + srow1 : M - 1;

    for (int k0 = 0; k0 < Kd; k0 += 32) {
        gload_lds16(A + (size_t)ga0 * lda + k0 + scol0, &As[(wid << 1) * 512]);
        gload_lds16(A + (size_t)ga1 * lda + k0 + scol1, &As[((wid << 1) + 1) * 512]);
        gload_lds16(B + (size_t)(bn + srow0) * ldb + k0 + scol0, &Bs[(wid << 1) * 512]);
        gload_lds16(B + (size_t)(bn + srow1) * ldb + k0 + scol1, &Bs[((wid << 1) + 1) * 512]);
        __syncthreads();
        short8 a[4], b[4];
        #pragma unroll
        for (int m = 0; m < 4; ++m) {
            int rr = wr + m * 16 + r0;
            a[m] = *(const short8*)(&As[rr * 32 + ((slotq ^ ((rr >> 1) & 3)) << 3)]);
        }
        #pragma unroll
        for (int n = 0; n < 4; ++n) {
            int rr = wc + n * 16 + r0;
            b[n] = *(const short8*)(&Bs[rr * 32 + ((slotq ^ ((rr >> 1) & 3)) << 3)]);
        }
        #pragma unroll
        for (int m = 0; m < 4; ++m)
            #pragma unroll
            for (int n = 0; n < 4; ++n)
                acc[m][n] = __builtin_amdgcn_mfma_f32_16x16x32_bf16(a[m], b[n], acc[m][n], 0, 0, 0);
        __syncthreads();
    }

    const int cr = (lane >> 4) * 4;
    const int cc = lane & 15;
    #pragma unroll
    for (int m = 0; m < 4; ++m) {
        #pragma unroll
        for (int j = 0; j < 4; ++j) {
            int row  = wr + m * 16 + cr + j;
            int grow = bm + row;
            float g = 1.0f;
            if (gate_mode) g = (grow < M) ? gatep[(size_t)grow * KS + z] : 0.f;
            int sw = ((row >> 2) & 3) << 5;
            #pragma unroll
            for (int n = 0; n < 4; ++n) {
                int col = wc + n * 16 + cc;
                float v = acc[m][n][j];
                if (biasp) v += biasp[bn + col];
                if (do_relu) v = fmaxf(v, 0.f);
                v *= g;
                *(ushort*)((char*)smem + row * 256 + ((col * 2) ^ sw)) = f2bf(v);
            }
        }
    }
    __syncthreads();
    #pragma unroll
    for (int it = 0; it < 8; ++it) {
        int row  = it * 16 + (tid >> 4);
        int grow = bm + row;
        int sw   = ((row >> 2) & 3) << 5;
        ushort8 vv = *(const ushort8*)((const char*)smem + row * 256 + (((tid & 15) * 16) ^ sw));
        if (grow < M)
            *(ushort8*)(Cout + (size_t)z * sC + (size_t)grow * ldc + bn + (tid & 15) * 8) = vv;
    }
}

// ======================================================================
// Fused symw-mix + symptom GEMM. A_virt[n][i] = sum_r symw[z][r]*
// aggb[n][r*256+i]. XCD-locality swizzle (bijective: 2512 = 8*314):
// launch j -> slot s = (j%8)*314 + j/8, so same-XCD blocks process
// consecutive slots -> a row-panel's 16 blocks land on one XCD's L2.
// SAFE now: catb and aggb are disjoint (layout race fixed).
// A reg-staged + swizzled ds_write; B via gload_lds.
// ======================================================================
__global__ __launch_bounds__(256) void gemm_amix(
    const ushort* __restrict__ aggb, const ushort* __restrict__ Wsym,
    const float* __restrict__ b_sym, const float* __restrict__ gatep,
    const float* __restrict__ symw, ushort* __restrict__ catb, int M)
{
    const int j = blockIdx.x + (blockIdx.y << 4);   // launch index (x fastest), 0..2511
    const int s = (j & 7) * 314 + (j >> 3);         // logical slot, same-XCD consecutive
    const int pnl = s >> 4;                         // row-panel (0..156)
    const int i   = s & 15;
    const int y   = i & 1;
    const int z   = i >> 1;
    const int bm  = pnl * 128;
    const int bn  = y * 128;
    const ushort* B = Wsym + (size_t)z * HDIM * HDIM;
    const float sw0 = symw[z * RT + 0], sw1 = symw[z * RT + 1];
    const float sw2 = symw[z * RT + 2], sw3 = symw[z * RT + 3];

    __shared__ ushort smem[128 * 128];
    ushort* As = smem;
    ushort* Bs = smem + 4096;

    const int tid  = threadIdx.x;
    const int lane = tid & 63;
    const int wid  = tid >> 6;
    const int wr   = (wid >> 1) * 64;
    const int wc   = (wid & 1) * 64;

    f32x4 acc[4][4];
    #pragma unroll
    for (int m = 0; m < 4; ++m)
        #pragma unroll
        for (int n = 0; n < 4; ++n)
            #pragma unroll
            for (int e = 0; e < 4; ++e) acc[m][n][e] = 0.f;

    const int r0    = lane & 15;
    const int slotq = lane >> 4;

    const int srow0 = ((wid << 1) << 4) + (lane >> 2);
    const int scol0 = (((lane & 3) ^ ((srow0 >> 1) & 3)) << 3);
    const int srow1 = srow0 + 16;
    const int scol1 = (((lane & 3) ^ ((srow1 >> 1) & 3)) << 3);

    const int arow0 = tid >> 2,          asl = tid & 3;
    const int arow1 = arow0 + 64;
    const int gaa0 = (bm + arow0 < M) ? bm + arow0 : M - 1;
    const int gaa1 = (bm + arow1 < M) ? bm + arow1 : M - 1;
    const int aoff0 = arow0 * 32 + ((asl ^ ((arow0 >> 1) & 3)) << 3);
    const int aoff1 = arow1 * 32 + ((asl ^ ((arow1 >> 1) & 3)) << 3);

    for (int k0 = 0; k0 < HDIM; k0 += 32) {
        gload_lds16(B + (size_t)(bn + srow0) * HDIM + k0 + scol0, &Bs[(wid << 1) * 512]);
        gload_lds16(B + (size_t)(bn + srow1) * HDIM + k0 + scol1, &Bs[((wid << 1) + 1) * 512]);
        {
            const ushort* ab0 = aggb + (size_t)gaa0 * (RT * HDIM) + k0 + asl * 8;
            const ushort* ab1 = aggb + (size_t)gaa1 * (RT * HDIM) + k0 + asl * 8;
            ushort8 u00 = *(const ushort8*)(ab0);
            ushort8 u01 = *(const ushort8*)(ab0 + HDIM);
            ushort8 u02 = *(const ushort8*)(ab0 + 2 * HDIM);
            ushort8 u03 = *(const ushort8*)(ab0 + 3 * HDIM);
            ushort8 u10 = *(const ushort8*)(ab1);
            ushort8 u11 = *(const ushort8*)(ab1 + HDIM);
            ushort8 u12 = *(const ushort8*)(ab1 + 2 * HDIM);
            ushort8 u13 = *(const ushort8*)(ab1 + 3 * HDIM);
            ushort8 o0, o1;
            #pragma unroll
            for (int jj = 0; jj < 8; ++jj) {
                o0[jj] = f2bf(sw0 * bf2f((ushort)u00[jj]) + sw1 * bf2f((ushort)u01[jj]) +
                              sw2 * bf2f((ushort)u02[jj]) + sw3 * bf2f((ushort)u03[jj]));
                o1[jj] = f2bf(sw0 * bf2f((ushort)u10[jj]) + sw1 * bf2f((ushort)u11[jj]) +
                              sw2 * bf2f((ushort)u12[jj]) + sw3 * bf2f((ushort)u13[jj]));
            }
            *(ushort8*)(&As[aoff0]) = o0;
            *(ushort8*)(&As[aoff1]) = o1;
        }
        __syncthreads();
        short8 a[4], b[4];
        #pragma unroll
        for (int m = 0; m < 4; ++m) {
            int rr = wr + m * 16 + r0;
            a[m] = *(const short8*)(&As[rr * 32 + ((slotq ^ ((rr >> 1) & 3)) << 3)]);
        }
        #pragma unroll
        for (int n = 0; n < 4; ++n) {
            int rr = wc + n * 16 + r0;
            b[n] = *(const short8*)(&Bs[rr * 32 + ((slotq ^ ((rr >> 1) & 3)) << 3)]);
        }
        #pragma unroll
        for (int m = 0; m < 4; ++m)
            #pragma unroll
            for (int n = 0; n < 4; ++n)
                acc[m][n] = __builtin_amdgcn_mfma_f32_16x16x32_bf16(a[m], b[n], acc[m][n], 0, 0, 0);
        __syncthreads();
    }

    const int cr = (lane >> 4) * 4;
    const int cc = lane & 15;
    #pragma unroll
    for (int m = 0; m < 4; ++m) {
        #pragma unroll
        for (int jj = 0; jj < 4; ++jj) {
            int row  = wr + m * 16 + cr + jj;
            int grow = bm + row;
            float g = (grow < M) ? gatep[(size_t)grow * KS + z] : 0.f;
            int sw = ((row >> 2) & 3) << 5;
            #pragma unroll
            for (int n = 0; n < 4; ++n) {
                int col = wc + n * 16 + cc;
                float v = acc[m][n][jj] + b_sym[z * HDIM + bn + col];
                v = fmaxf(v, 0.f) * g;
                *(ushort*)((char*)smem + row * 256 + ((col * 2) ^ sw)) = f2bf(v);
            }
        }
    }
    __syncthreads();
    #pragma unroll
    for (int it = 0; it < 8; ++it) {
        int row  = it * 16 + (tid >> 4);
        int grow = bm + row;
        int sw   = ((row >> 2) & 3) << 5;
        ushort8 vv = *(const ushort8*)((const char*)smem + row * 256 + (((tid & 15) * 16) ^ sw));
        if (grow < M)
            *(ushort8*)(catb + (size_t)grow * (KS * HDIM) + z * HDIM + bn + (tid & 15) * 8) = vv;
    }
}

// gate: logits = hid @ w2.T + b2 ; softmax over K. One wave per node. hid bf16.
__global__ __launch_bounds__(256) void gate_kernel(
    const ushort* __restrict__ hid, const float* __restrict__ w2,
    const float* __restrict__ b2, float* __restrict__ gate)
{
    int wid = threadIdx.x >> 6, lane = threadIdx.x & 63;
    int n = blockIdx.x * 4 + wid;
    if (n >= NN) return;
    ushort4 h4 = *(const ushort4*)(hid + (size_t)n * HDIM + lane * 4);
    float hx = bf2f(h4.x), hy = bf2f(h4.y), hz = bf2f(h4.z), hw = bf2f(h4.w);
    float lg[KS];
    #pragma unroll
    for (int k = 0; k < KS; ++k) {
        const float4 wv = *(const float4*)(w2 + k * HDIM + lane * 4);
        float p = hx * wv.x + hy * wv.y + hz * wv.z + hw * wv.w;
        #pragma unroll
        for (int m = 1; m < 64; m <<= 1) p += __shfl_xor(p, m);
        lg[k] = p + b2[k];
    }
    float m = lg[0];
    #pragma unroll
    for (int k = 1; k < KS; ++k) m = fmaxf(m, lg[k]);
    float ssum = 0.f;
    #pragma unroll
    for (int k = 0; k < KS; ++k) ssum += __expf(lg[k] - m);
    float inv = 1.0f / ssum;
    #pragma unroll
    for (int k = 0; k < KS; ++k)
        if (lane == k) gate[(size_t)n * KS + k] = __expf(lg[k] - m) * inv;
}

// residual + layernorm. One wave per node. hnew bf16.
__global__ __launch_bounds__(256) void ln_kernel(
    const float* __restrict__ h, const ushort* __restrict__ hnew,
    const float* __restrict__ gamma, const float* __restrict__ beta,
    float* __restrict__ out)
{
    int wid = threadIdx.x >> 6, lane = threadIdx.x & 63;
    int n = blockIdx.x * 4 + wid;
    if (n >= NN) return;
    size_t off = (size_t)n * HDIM + lane * 4;
    const float4 a = *(const float4*)(h + off);
    ushort4 b4 = *(const ushort4*)(hnew + off);
    float4 x = make_float4(a.x + bf2f(b4.x), a.y + bf2f(b4.y),
                           a.z + bf2f(b4.z), a.w + bf2f(b4.w));
    float s1 = x.x + x.y + x.z + x.w;
    float s2 = x.x * x.x + x.y * x.y + x.z * x.z + x.w * x.w;
    #pragma unroll
    for (int m = 1; m < 64; m <<= 1) { s1 += __shfl_xor(s1, m); s2 += __shfl_xor(s2, m); }
    float mu = s1 * (1.0f / HDIM);
    float var = s2 * (1.0f / HDIM) - mu * mu;
    float inv = rsqrtf(var + LN_EPS);
    const float4 g  = *(const float4*)(gamma + lane * 4);
    const float4 be = *(const float4*)(beta + lane * 4);
    float4 o;
    o.x = (x.x - mu) * inv * g.x + be.x;
    o.y = (x.y - mu) * inv * g.y + be.y;
    o.z = (x.z - mu) * inv * g.z + be.z;
    o.w = (x.w - mu) * inv * g.w + be.w;
    *(float4*)(out + off) = o;
}

extern "C" void kernel_launch(void* const* d_in, const int* in_sizes, int n_in,
                              void* d_out, int out_size, void* d_ws, size_t ws_size,
                              hipStream_t stream) {
    const float* h          = (const float*)d_in[0];
    const int*   edge_index = (const int*)d_in[1];
    const int*   edge_type  = (const int*)d_in[2];
    const float* W_q        = (const float*)d_in[3];
    const float* W_k        = (const float*)d_in[4];
    const float* W_v        = (const float*)d_in[5];
    const float* mlp_w1     = (const float*)d_in[6];
    const float* mlp_b1     = (const float*)d_in[7];
    const float* mlp_w2     = (const float*)d_in[8];
    const float* mlp_b2     = (const float*)d_in[9];
    const float* sym_logits = (const float*)d_in[10];
    const float* W_sym      = (const float*)d_in[11];
    const float* b_sym      = (const float*)d_in[12];
    const float* W_cross    = (const float*)d_in[13];
    const float* b_cross    = (const float*)d_in[14];
    const float* ln_gamma   = (const float*)d_in[15];
    const float* ln_beta    = (const float*)d_in[16];
    float* out = (float*)d_out;
    char*  ws  = (char*)d_ws;

    ushort* qkv    = (ushort*)(ws + OFFB_QKV);
    ushort* catb   = (ushort*)(ws + OFFB_CATB);  // overlays dead qkv planes 0-7
    ushort* hnew   = (ushort*)(ws + OFFB_HNEW);  // overlays dead qkv plane 8
    ushort* hid    = (ushort*)(ws + OFFB_HID);   // == qkv + 12*sNH (contiguous plane 12)
    ushort* aggb   = (ushort*)(ws + OFFB_AGGB);  // disjoint from catb/hnew
    ushort* hb     = (ushort*)(ws + OFFB_HB);
    float*  gate   = (float*)(ws + OFFB_GATE);
    ushort* wqkvb  = (ushort*)(ws + OFFB_WQKV);
    ushort* w1b    = (ushort*)(ws + OFFB_W1);    // == wqkvb + 12*H*H (contiguous)
    ushort* wsymb  = (ushort*)(ws + OFFB_WSYM);
    ushort* wxb    = (ushort*)(ws + OFFB_WX);
    float*  symw   = (float*)(ws + OFFB_SYMW);
    int*    cnt    = (int*)(ws + OFFB_CNT);
    int*    rp     = (int*)(ws + OFFB_RP);
    int*    bsum   = (int*)(ws + OFFB_BSUM);
    int*    cursor = (int*)(ws + OFFB_CUR);
    int*    esrc   = (int*)(ws + OFFB_ESRC);

    const long long sRHH = (long long)RT * HDIM * HDIM;   // per-mat weight stride
    const long long sNH  = (long long)NN * HDIM;          // per-z output stride

    // ---- conversions ----
    cvt_bf16_kernel<<<5000, 256, 0, stream>>>(h, hb, NN * HDIM / 4);
    cvt_bf16_kernel<<<256, 256, 0, stream>>>(W_q, wqkvb,            RT * HDIM * HDIM / 4);
    cvt_bf16_kernel<<<256, 256, 0, stream>>>(W_k, wqkvb + sRHH,     RT * HDIM * HDIM / 4);
    cvt_bf16_kernel<<<256, 256, 0, stream>>>(W_v, wqkvb + 2 * sRHH, RT * HDIM * HDIM / 4);
    cvt_bf16_kernel<<<64, 256, 0, stream>>>(mlp_w1, w1b, HDIM * HDIM / 4);
    cvt_bf16_kernel<<<512, 256, 0, stream>>>(W_sym, wsymb, KS * HDIM * HDIM / 4);
    cvt_bf16_kernel<<<512, 256, 0, stream>>>(W_cross, wxb, HDIM * KS * HDIM / 4);
    symw_kernel<<<1, 64, 0, stream>>>(sym_logits, symw);

    // ---- QKV + routing-MLP in ONE batched GEMM (z<12: qkv; z==12: hid) ----
    gemm_bf16_nt<<<dim3(26, 157, 1), 256, 0, stream>>>(hb, wqkvb, mlp_b1, nullptr, qkv,
        NN, HDIM, HDIM, HDIM, HDIM, 0, (long long)HDIM * HDIM, 0, sNH, 0, 0, 1, 12);

    gate_kernel<<<NN / 4, 256, 0, stream>>>(hid, mlp_w2, mlp_b2, gate);

    // ---- CSR build over seg = t*N + dst ----
    hipMemsetAsync(cnt, 0, NSEG * sizeof(int), stream);
    hist_kernel<<<NE / 256, 256, 0, stream>>>(edge_index, edge_type, cnt);
    scan1_kernel<<<79, 256, 0, stream>>>(cnt, rp, bsum);
    scan2_kernel<<<1, 256, 0, stream>>>(bsum, 79);
    scan3_kernel<<<313, 256, 0, stream>>>(rp, bsum, cursor);
    reorder_kernel<<<NE / 256, 256, 0, stream>>>(edge_index, edge_type, cursor, esrc);

    // ---- gather attention: one wave per segment, single pass, dual chains ----
    attn_kernel<<<NSEG / 4, 256, 0, stream>>>(qkv, esrc, rp, aggb);

    // ---- FUSED symw-mix + symptom GEMM -> catb (over dead qkv planes 0-7) ----
    gemm_amix<<<dim3(16, 157), 256, 0, stream>>>(aggb, wsymb, b_sym, gate, symw, catb, NN);

    // ---- cross GEMM: hnew = relu(catb @ W_cross.T + b_cross), swap2 ----
    gemm_bf16_nt<<<dim3(2, 157, 1), 256, 0, stream>>>(catb, wxb, b_cross, nullptr, hnew,
        NN, KS * HDIM, KS * HDIM, KS * HDIM, HDIM, 0, 0, 0, 0, 1, 0, 1, -1);

    // ---- residual + layernorm ----
    ln_kernel<<<NN / 4, 256, 0, stream>>>(h, hnew, ln_gamma, ln_beta, out);
}